// Round 7
// baseline (312.496 us; speedup 1.0000x reference)
//
#include <hip/hip_runtime.h>

#define T_SEQ 2048
#define BATCH 2
#define HEADS 8
#define DHEAD 64
#define EMB   512
#define NSPLIT 2

typedef __attribute__((ext_vector_type(8))) short short8;
typedef __attribute__((ext_vector_type(4))) float floatx4;
typedef __attribute__((ext_vector_type(8))) unsigned short ushort8;
typedef __attribute__((ext_vector_type(4))) unsigned short ushort4v;

// RNE convert (cold paths)
__device__ __forceinline__ unsigned short f2b(float f) {
    union { float f; unsigned u; } v; v.f = f;
    unsigned r = v.u + 0x7fffu + ((v.u >> 16) & 1u);
    return (unsigned short)(r >> 16);
}
// 1-op truncating convert (hot paths)
__device__ __forceinline__ unsigned short f2bt(float f) {
    union { float f; unsigned u; } v; v.f = f;
    return (unsigned short)(v.u >> 16);
}
__device__ __forceinline__ float b2f(unsigned short s) {
    union { unsigned u; float f; } v; v.u = ((unsigned)s) << 16; return v.f;
}
__device__ __forceinline__ short8 ld16(const unsigned short* p) {
    return *(const short8*)p;
}
__device__ __forceinline__ void st8(unsigned short* p, ushort8 v) {
    *(ushort8*)p = v;
}
#define MFMA16(a, b, c) __builtin_amdgcn_mfma_f32_16x16x32_bf16(a, b, c, 0, 0, 0)

// ---------------------------------------------------------------------------
// One-shot fp32 -> bf16 conversion of all 5 tensors.
// float4 segments: input 524288 | pos 262144 | w_in 196608 | w_pos 65536 |
// w_out 65536 (total 1114112)
// ---------------------------------------------------------------------------
__global__ __launch_bounds__(256)
void cvt_all(const float* __restrict__ s0, const float* __restrict__ s1,
             const float* __restrict__ s2, const float* __restrict__ s3,
             const float* __restrict__ s4,
             unsigned short* __restrict__ d0, unsigned short* __restrict__ d1,
             unsigned short* __restrict__ d2, unsigned short* __restrict__ d3,
             unsigned short* __restrict__ d4)
{
    const int i = blockIdx.x * 256 + threadIdx.x;
    const float* s; unsigned short* d; int off;
    if      (i <  524288) { s = s0; d = d0; off = i; }
    else if (i <  786432) { s = s1; d = d1; off = i -  524288; }
    else if (i <  983040) { s = s2; d = d2; off = i -  786432; }
    else if (i < 1048576) { s = s3; d = d3; off = i -  983040; }
    else if (i < 1114112) { s = s4; d = d4; off = i - 1048576; }
    else return;
    const float4 v = ((const float4*)s)[off];
    ushort4v o = { f2b(v.x), f2b(v.y), f2b(v.z), f2b(v.w) };
    ((ushort4v*)d)[off] = o;
}

// ---------------------------------------------------------------------------
// bf16 MFMA GEMM: C[m,n] = sum_k A[m,k]*B[n,k] + bias[n]
// 128x128 tile, 4 waves 2x2, BK=32. All dims exact multiples.
// MODE 0: QKV -> q_s/k_s/v_s bf16 [B,H,T,D] (coalesced dd-contiguous writes)
// MODE 1: pos -> r bf16 [R,E];  MODE 2: out -> fp32 [m*EMB+n]
// ---------------------------------------------------------------------------
template<int MODE>
__global__ __launch_bounds__(256)
void gemm_bf16(const unsigned short* __restrict__ A, const unsigned short* __restrict__ B,
               const float* __restrict__ bias, void* __restrict__ out0,
               void* __restrict__ out1, void* __restrict__ out2, int K)
{
    __shared__ unsigned short As[128 * 36];
    __shared__ unsigned short Bs[128 * 36];
    const int bm  = blockIdx.y * 128;
    const int bn  = blockIdx.x * 128;
    const int tid = threadIdx.x;
    const int lane = tid & 63, w = tid >> 6;
    const int m16 = lane & 15, quad = lane >> 4;
    const int wm = (w & 1) * 64, wn = (w >> 1) * 64;

    floatx4 acc[4][4];
    #pragma unroll
    for (int i = 0; i < 4; ++i)
        #pragma unroll
        for (int j = 0; j < 4; ++j) acc[i][j] = (floatx4){0.f, 0.f, 0.f, 0.f};

    for (int k0 = 0; k0 < K; k0 += 32) {
        #pragma unroll
        for (int s = tid; s < 512; s += 256) {
            const int row = s >> 2, c = (s & 3) * 8;
            st8(&As[row * 36 + c], *(const ushort8*)(A + (size_t)(bm + row) * K + k0 + c));
            st8(&Bs[row * 36 + c], *(const ushort8*)(B + (size_t)(bn + row) * K + k0 + c));
        }
        __syncthreads();
        short8 af[4], bf[4];
        #pragma unroll
        for (int f = 0; f < 4; ++f) {
            af[f] = ld16(&As[(wm + f * 16 + m16) * 36 + quad * 8]);
            bf[f] = ld16(&Bs[(wn + f * 16 + m16) * 36 + quad * 8]);
        }
        #pragma unroll
        for (int fm = 0; fm < 4; ++fm)
            #pragma unroll
            for (int fn = 0; fn < 4; ++fn)
                acc[fm][fn] = MFMA16(af[fm], bf[fn], acc[fm][fn]);
        __syncthreads();
    }

    #pragma unroll
    for (int fn = 0; fn < 4; ++fn) {
        const int n = bn + wn + fn * 16 + m16;
        const float bv = bias[n];
        #pragma unroll
        for (int fm = 0; fm < 4; ++fm) {
            #pragma unroll
            for (int rgi = 0; rgi < 4; ++rgi) {
                const int m = bm + wm + fm * 16 + quad * 4 + rgi;
                const float val = acc[fm][fn][rgi] + bv;
                if (MODE == 0) {
                    const int t = m >> 1, b = m & 1;
                    const int reg = n >> 9, c = n & 511, h = c >> 6, dd = c & 63;
                    unsigned short* dst = (unsigned short*)(reg == 0 ? out0 : (reg == 1 ? out1 : out2));
                    dst[((size_t)(b * HEADS + h) * T_SEQ + t) * DHEAD + dd] = f2b(val);
                } else if (MODE == 1) {
                    ((unsigned short*)out0)[(size_t)m * EMB + n] = f2b(val);
                } else {
                    ((float*)out0)[(size_t)m * EMB + n] = val;
                }
            }
        }
    }
}

// ---------------------------------------------------------------------------
// bf16 transpose: v_s [B,H,T,D] -> vT [B,H,D,T] (coalesced both sides via LDS)
// ---------------------------------------------------------------------------
__global__ __launch_bounds__(256)
void transpose_v(const unsigned short* __restrict__ v_s, unsigned short* __restrict__ vT)
{
    __shared__ unsigned short tile[64 * 68];
    const int t0 = blockIdx.x * 64, bh = blockIdx.y;
    const int tid = threadIdx.x;
    const unsigned short* src = v_s + ((size_t)bh * T_SEQ + t0) * DHEAD;
    #pragma unroll
    for (int s = tid; s < 512; s += 256) {
        const int row = s >> 3, c = (s & 7) * 8;
        *(ushort8*)&tile[row * 68 + c] = *(const ushort8*)(src + row * DHEAD + c);
    }
    __syncthreads();
    unsigned short* dst = vT + (size_t)bh * DHEAD * T_SEQ + t0;
    #pragma unroll
    for (int s = tid; s < 512; s += 256) {
        const int d = s >> 3, c = (s & 7) * 8;
        ushort8 o;
        #pragma unroll
        for (int j = 0; j < 8; ++j) o[j] = tile[(c + j) * 68 + d];
        *(ushort8*)(dst + (size_t)d * T_SEQ + c) = o;
    }
}

// ---------------------------------------------------------------------------
// Split-s fused MFMA attention, rolling-QR ring, no-max exp2 softmax,
// deferred l-reduction, V staged late into the K buffer (35.6 KB -> 4 blk/CU).
//   bd[t][s] = QR[t][T-1-t+s] (s<=t) | 0 (s==t+1) | QR[t+1][s-t-2] (s>=t+2)
// q pre-scaled by 0.125*log2(e) so P = exp2(score).
// LDS (u16 offs): region0 @0 64x72 [qrw | r_s | p_s] ; region1 @4608 65x72
// [qrr | k_ls -> v_ls] ; qp ring @9288 64x133.  Total 35600 B.
// ---------------------------------------------------------------------------
__global__ __launch_bounds__(256)
void attn_mfma(const unsigned short* __restrict__ qg_, const unsigned short* __restrict__ kg_,
               const unsigned short* __restrict__ vtg_, const unsigned short* __restrict__ rg_,
               const float* __restrict__ rwb, const float* __restrict__ rrb,
               unsigned short* __restrict__ pO, float* __restrict__ pml)
{
    const int T   = T_SEQ;
    const int tb  = blockIdx.x;
    const int t0  = tb * 64;
    const int bh  = blockIdx.y;
    const int sp  = blockIdx.z;
    const int ss  = sp * (T / NSPLIT);
    const int se  = ss + (T / NSPLIT);
    const int h   = bh & 7;
    const int tid = threadIdx.x;
    const int lane = tid & 63;
    const int w    = tid >> 6;
    const int m16  = lane & 15;
    const int quad = lane >> 4;
    const int ibase = 16 * w + quad * 4;

    __shared__ unsigned short lds[17800];
    unsigned short* qrw_s = lds;            // 64 x 72 (pre-loop)
    unsigned short* qrr_s = lds + 4608;     // 65 x 72 (pre-loop)
    unsigned short* r_s   = lds;            // in-loop alias
    unsigned short* p_s   = lds;            // P tile alias
    unsigned short* k_ls  = lds + 4608;     // K tile (AC phase)
    unsigned short* v_ls  = lds + 4608;     // V tile (PV phase, after K dead)
    unsigned short* qp_s  = lds + 9288;     // 64 x 133 ring

    const unsigned short* qg  = qg_  + ((size_t)bh * T + t0) * DHEAD;
    const unsigned short* kg  = kg_  + (size_t)bh * T * DHEAD;
    const unsigned short* vtg = vtg_ + (size_t)bh * DHEAD * T;
    const unsigned short* rg  = rg_  + h * DHEAD;

    // ---- stage q tiles: (q + bias) * 0.125 * log2e ----
    const float QSCALE = 0.125f * 1.44269504089f;
    for (int idx = tid; idx < 65 * 16; idx += 256) {
        const int row = idx >> 4, c = (idx & 15) << 2;
        ushort4v qv = {0, 0, 0, 0};
        if (t0 + row < T) qv = *(const ushort4v*)(qg + row * DHEAD + c);
        const float4 rr = *(const float4*)(rrb + h * DHEAD + c);
        qrr_s[row * 72 + c + 0] = f2b((b2f(qv[0]) + rr.x) * QSCALE);
        qrr_s[row * 72 + c + 1] = f2b((b2f(qv[1]) + rr.y) * QSCALE);
        qrr_s[row * 72 + c + 2] = f2b((b2f(qv[2]) + rr.z) * QSCALE);
        qrr_s[row * 72 + c + 3] = f2b((b2f(qv[3]) + rr.w) * QSCALE);
        if (row < 64) {
            const float4 rw = *(const float4*)(rwb + h * DHEAD + c);
            qrw_s[row * 72 + c + 0] = f2b((b2f(qv[0]) + rw.x) * QSCALE);
            qrw_s[row * 72 + c + 1] = f2b((b2f(qv[1]) + rw.y) * QSCALE);
            qrw_s[row * 72 + c + 2] = f2b((b2f(qv[2]) + rw.z) * QSCALE);
            qrw_s[row * 72 + c + 3] = f2b((b2f(qv[3]) + rw.w) * QSCALE);
        }
    }
    __syncthreads();

    short8 a_ac[2], a_qrl[2], a_qru[2];
    {
        const unsigned short* p0 = &qrw_s[(16 * w + m16) * 72 + quad * 8];
        a_ac[0]  = ld16(p0);  a_ac[1]  = ld16(p0 + 32);
        const unsigned short* p1 = &qrr_s[(16 * w + m16) * 72 + quad * 8];
        a_qrl[0] = ld16(p1);  a_qrl[1] = ld16(p1 + 32);
        const unsigned short* p2 = &qrr_s[(16 * w + 1 + m16) * 72 + quad * 8];
        a_qru[0] = ld16(p2);  a_qru[1] = ld16(p2 + 32);
    }
    __syncthreads();   // q regions now reusable

    auto stage_r = [&](int jbase) {
        #pragma unroll
        for (int idx = tid; idx < 512; idx += 256) {
            const int row = idx >> 3, c = (idx & 7) * 8;
            int j = jbase + row; j = j < 0 ? 0 : (j > T - 1 ? T - 1 : j);
            st8(&r_s[row * 72 + c], *(const ushort8*)(rg + (size_t)j * EMB + c));
        }
    };
    auto qr_half = [&](const short8* aq, int slotbase) {
        #pragma unroll
        for (int cc = 0; cc < 4; ++cc) {
            floatx4 q4 = (floatx4){0.f, 0.f, 0.f, 0.f};
            #pragma unroll
            for (int ks = 0; ks < 2; ++ks) {
                short8 bfr = ld16(&r_s[(16 * cc + m16) * 72 + ks * 32 + quad * 8]);
                q4 = MFMA16(aq[ks], bfr, q4);
            }
            #pragma unroll
            for (int rgi = 0; rgi < 4; ++rgi)
                qp_s[(ibase + rgi) * 133 + slotbase + 16 * cc + m16] = f2bt(q4[rgi]);
        }
    };

    floatx4 O[4];
    float lrun[4];   // per-lane partial row sums (reduced at epilogue)
    #pragma unroll
    for (int ct = 0; ct < 4; ++ct) O[ct] = (floatx4){0.f, 0.f, 0.f, 0.f};
    #pragma unroll
    for (int rgi = 0; rgi < 4; ++rgi) lrun[rgi] = 0.f;

    // ---- prologue: fill the "old" 64 window cols for the first tile ----
    {
        const bool startLower = (ss <= t0);
        const int wstart0 = startLower ? (ss + T - t0 - 64) : (ss - t0 - 65);
        const int n0      = startLower ? (ss >> 6) : ((ss - t0) >> 6);
        stage_r(wstart0);
        __syncthreads();
        qr_half(startLower ? a_qrl : a_qru, (n0 & 1) * 64);
    }

    for (int s0 = ss; s0 < se; s0 += 64) {
        const bool lower = (s0 <= t0);
        const int n      = lower ? (s0 >> 6) : ((s0 - t0) >> 6);
        const int rbase  = (n & 1) * 64;
        const int wbase  = 64 - rbase;
        const int wstart = lower ? (s0 + T - t0 - 64) : (s0 - t0 - 65);

        __syncthreads();   // B_top: prior PV/P/qp reads done

        // ---- stage K + new 64 r rows ----
        #pragma unroll
        for (int idx = tid; idx < 512; idx += 256) {
            const int row = idx >> 3, c = (idx & 7) * 8;
            st8(&k_ls[row * 72 + c], *(const ushort8*)(kg + (size_t)(s0 + row) * DHEAD + c));
        }
        stage_r(wstart + 64);
        __syncthreads();   // B0

        // ---- AC ----
        floatx4 acf[4];
        #pragma unroll
        for (int ct = 0; ct < 4; ++ct) {
            acf[ct] = (floatx4){0.f, 0.f, 0.f, 0.f};
            #pragma unroll
            for (int ks = 0; ks < 2; ++ks) {
                short8 bfr = ld16(&k_ls[(16 * ct + m16) * 72 + ks * 32 + quad * 8]);
                acf[ct] = MFMA16(a_ac[ks], bfr, acf[ct]);
            }
        }
        // ---- QR: new 64 window cols -> ring ----
        qr_half(lower ? a_qrl : a_qru, wbase);
        __syncthreads();   // B1 (K and r reads done)

        // ---- stage V into the (dead) K region ----
        #pragma unroll
        for (int idx = tid; idx < 512; idx += 256) {
            const int row = idx >> 3, c = (idx & 7) * 8;
            st8(&v_ls[row * 72 + c], *(const ushort8*)(vtg + (size_t)row * T + s0 + c));
        }

        // ---- assemble from ring (specialized) ----
        if (s0 != t0) {
            #pragma unroll
            for (int ct = 0; ct < 4; ++ct) {
                #pragma unroll
                for (int rgi = 0; rgi < 4; ++rgi) {
                    const int i = ibase + rgi;
                    const int slot = ((63 - i + 16 * ct + m16) + rbase) & 127;
                    acf[ct][rgi] += b2f(qp_s[i * 133 + slot]);
                }
            }
            if (s0 == t0 + 64 && lane == 48 && w == 3)
                acf[0][3] -= b2f(qp_s[63 * 133 + (rbase & 127)]);
        } else {
            // DIAG pass 1: lower-masked
            #pragma unroll
            for (int ct = 0; ct < 4; ++ct) {
                #pragma unroll
                for (int rgi = 0; rgi < 4; ++rgi) {
                    const int i = ibase + rgi, u = 16 * ct + m16;
                    if (u <= i) acf[ct][rgi] += b2f(qp_s[i * 133 + (((63 - i + u) + rbase) & 127)]);
                }
            }
            // DIAG pass 2: upper prologue (slots 64..127 <- j = -1..62) + assemble
            __syncthreads();
            stage_r(-1);
            __syncthreads();
            qr_half(a_qru, 64);
            __syncthreads();
            #pragma unroll
            for (int ct = 0; ct < 4; ++ct) {
                #pragma unroll
                for (int rgi = 0; rgi < 4; ++rgi) {
                    const int i = ibase + rgi, u = 16 * ct + m16;
                    if (u >= i + 2) acf[ct][rgi] += b2f(qp_s[i * 133 + 63 - i + u]);
                }
            }
        }

        // ---- no-max exp2 softmax, per-lane l accumulation ----
        #pragma unroll
        for (int rgi = 0; rgi < 4; ++rgi) {
            #pragma unroll
            for (int ct = 0; ct < 4; ++ct) {
                const float p = exp2f(acf[ct][rgi]);
                acf[ct][rgi] = p;
                lrun[rgi] += p;
            }
        }

        // ---- write P (region0; r reads finished at B1) ----
        #pragma unroll
        for (int ct = 0; ct < 4; ++ct)
            #pragma unroll
            for (int rgi = 0; rgi < 4; ++rgi)
                p_s[(ibase + rgi) * 72 + 16 * ct + m16] = f2bt(acf[ct][rgi]);
        __syncthreads();   // B2

        // ---- PV ----
        short8 ap[2];
        {
            const unsigned short* p = &p_s[(16 * w + m16) * 72 + quad * 8];
            ap[0] = ld16(p); ap[1] = ld16(p + 32);
        }
        #pragma unroll
        for (int ct = 0; ct < 4; ++ct) {
            #pragma unroll
            for (int ks = 0; ks < 2; ++ks) {
                short8 bfr = ld16(&v_ls[(16 * ct + m16) * 72 + ks * 32 + quad * 8]);
                O[ct] = MFMA16(ap[ks], bfr, O[ct]);
            }
        }
    }

    // ---- epilogue: reduce l across the 16 lanes of each row, write partials ----
    unsigned short* po = pO + (((size_t)sp * 16 + bh) * 32 + tb) * 4096;
    float* ml          = pml + (((size_t)sp * 16 + bh) * 32 + tb) * 64;
    #pragma unroll
    for (int rgi = 0; rgi < 4; ++rgi) {
        float l = lrun[rgi];
        #pragma unroll
        for (int off = 1; off < 16; off <<= 1)
            l += __shfl_xor(l, off);
        const int i = ibase + rgi;
        #pragma unroll
        for (int ct = 0; ct < 4; ++ct)
            po[i * 64 + 16 * ct + m16] = f2bt(O[ct][rgi]);
        if (m16 == 0) ml[i] = l;
    }
}

// ---------------------------------------------------------------------------
// Merge NSPLIT partials -> ctx bf16 [T,B,E]
// ---------------------------------------------------------------------------
__global__ __launch_bounds__(256)
void merge_attn(const unsigned short* __restrict__ pO, const float* __restrict__ pml,
                unsigned short* __restrict__ ctx)
{
    const int tb = blockIdx.x, bh = blockIdx.y;
    const int h = bh & 7, b = bh >> 3;
    const int tid = threadIdx.x;
    const int row = tid >> 2, cseg = (tid & 3) * 16;

    const size_t blk0 = (((size_t)0 * 16 + bh) * 32 + tb);
    const size_t blk1 = (((size_t)1 * 16 + bh) * 32 + tb);
    const float inv = 1.f / (pml[blk0 * 64 + row] + pml[blk1 * 64 + row]);

    const unsigned short* o0 = pO + blk0 * 4096 + row * 64 + cseg;
    const unsigned short* o1 = pO + blk1 * 4096 + row * 64 + cseg;
    unsigned short* dst = ctx + ((size_t)(tb * 64 + row) * BATCH + b) * EMB + h * 64 + cseg;
    ushort8 a0 = *(const ushort8*)o0, a1 = *(const ushort8*)o1;
    ushort8 b0 = *(const ushort8*)(o0 + 8), b1 = *(const ushort8*)(o1 + 8);
    ushort8 r0, r1;
    #pragma unroll
    for (int j = 0; j < 8; ++j) {
        r0[j] = f2b((b2f(a0[j]) + b2f(a1[j])) * inv);
        r1[j] = f2b((b2f(b0[j]) + b2f(b1[j])) * inv);
    }
    *(ushort8*)dst = r0;
    *(ushort8*)(dst + 8) = r1;
}

// ---------------------------------------------------------------------------
// Workspace (ushort offsets), 15,990,784 ush = 31.98 MB:
//   0        inb     2,097,152  \ dead after GEMMs -> overlay:
//   2097152  posb    1,048,576   |  pO bf16 @0 (4,194,304 ush)
//   3145728  w_inb     786,432   |
//   3932160  w_posb    262,144  /
//   4194304  v_s     2,097,152  (dead after transpose) -> pml fp32 overlay
//   6291456  w_outb    262,144
//   6553600  q_s     2,097,152
//   8650752  k_s     2,097,152
//   10747904 vT      2,097,152
//   12845056 r_b     1,048,576
//   13893632 ctx_b   2,097,152
// ---------------------------------------------------------------------------
extern "C" void kernel_launch(void* const* d_in, const int* in_sizes, int n_in,
                              void* d_out, int out_size, void* d_ws, size_t ws_size,
                              hipStream_t stream)
{
    const float* input = (const float*)d_in[0];
    const float* pos   = (const float*)d_in[1];
    const float* w_in  = (const float*)d_in[2];
    const float* w_out = (const float*)d_in[3];
    const float* w_pos = (const float*)d_in[4];
    const float* b_in  = (const float*)d_in[5];
    const float* b_out = (const float*)d_in[6];
    const float* b_pos = (const float*)d_in[7];
    const float* rwb   = (const float*)d_in[8];
    const float* rrb   = (const float*)d_in[9];

    unsigned short* ws     = (unsigned short*)d_ws;
    unsigned short* inb    = ws;
    unsigned short* posb   = ws + 2097152;
    unsigned short* w_inb  = ws + 3145728;
    unsigned short* w_posb = ws + 3932160;
    unsigned short* v_s    = ws + 4194304;
    unsigned short* w_outb = ws + 6291456;
    unsigned short* q_s    = ws + 6553600;
    unsigned short* k_s    = ws + 8650752;
    unsigned short* vT     = ws + 10747904;
    unsigned short* r_b    = ws + 12845056;
    unsigned short* ctx_b  = ws + 13893632;
    unsigned short* pO     = ws;                       // overlay
    float*          pml    = (float*)(ws + 4194304);   // overlay (v_s dead)

    cvt_all<<<4352, 256, 0, stream>>>(input, pos, w_in, w_pos, w_out,
                                      inb, posb, w_inb, w_posb, w_outb);
    gemm_bf16<0><<<dim3(12, 32), 256, 0, stream>>>(inb, w_inb, b_in, q_s, k_s, v_s, EMB);
    gemm_bf16<1><<<dim3(4, 16), 256, 0, stream>>>(posb, w_posb, b_pos, r_b, nullptr, nullptr, EMB);
    transpose_v<<<dim3(32, 16), 256, 0, stream>>>(v_s, vT);
    attn_mfma<<<dim3(32, 16, NSPLIT), 256, 0, stream>>>(q_s, k_s, vT, r_b, rwb, rrb, pO, pml);
    merge_attn<<<dim3(32, 16), 256, 0, stream>>>(pO, pml, ctx_b);
    gemm_bf16<2><<<dim3(4, 32), 256, 0, stream>>>(ctx_b, w_outb, b_out, d_out, nullptr, nullptr, EMB);
}

// Round 9
// 264.037 us; speedup vs baseline: 1.1835x; 1.1835x over previous
//
#include <hip/hip_runtime.h>

#define T_SEQ 2048
#define BATCH 2
#define HEADS 8
#define DHEAD 64
#define EMB   512
#define NSPLIT 2

typedef __attribute__((ext_vector_type(8))) short short8;
typedef __attribute__((ext_vector_type(4))) float floatx4;
typedef __attribute__((ext_vector_type(8))) unsigned short ushort8;
typedef __attribute__((ext_vector_type(4))) unsigned short ushort4v;

// RNE convert (cold paths)
__device__ __forceinline__ unsigned short f2b(float f) {
    union { float f; unsigned u; } v; v.f = f;
    unsigned r = v.u + 0x7fffu + ((v.u >> 16) & 1u);
    return (unsigned short)(r >> 16);
}
// 1-op truncating convert (hot paths)
__device__ __forceinline__ unsigned short f2bt(float f) {
    union { float f; unsigned u; } v; v.f = f;
    return (unsigned short)(v.u >> 16);
}
__device__ __forceinline__ float b2f(unsigned short s) {
    union { unsigned u; float f; } v; v.u = ((unsigned)s) << 16; return v.f;
}
__device__ __forceinline__ short8 ld16(const unsigned short* p) {
    return *(const short8*)p;
}
#define MFMA16(a, b, c) __builtin_amdgcn_mfma_f32_16x16x32_bf16(a, b, c, 0, 0, 0)

// ---------------------------------------------------------------------------
// One-shot fp32 -> bf16 conversion of all 5 tensors.
// ---------------------------------------------------------------------------
__global__ __launch_bounds__(256)
void cvt_all(const float* __restrict__ s0, const float* __restrict__ s1,
             const float* __restrict__ s2, const float* __restrict__ s3,
             const float* __restrict__ s4,
             unsigned short* __restrict__ d0, unsigned short* __restrict__ d1,
             unsigned short* __restrict__ d2, unsigned short* __restrict__ d3,
             unsigned short* __restrict__ d4)
{
    const int i = blockIdx.x * 256 + threadIdx.x;
    const float* s; unsigned short* d; int off;
    if      (i <  524288) { s = s0; d = d0; off = i; }
    else if (i <  786432) { s = s1; d = d1; off = i -  524288; }
    else if (i <  983040) { s = s2; d = d2; off = i -  786432; }
    else if (i < 1048576) { s = s3; d = d3; off = i -  983040; }
    else if (i < 1114112) { s = s4; d = d4; off = i - 1048576; }
    else return;
    const float4 v = ((const float4*)s)[off];
    ushort4v o = { f2b(v.x), f2b(v.y), f2b(v.z), f2b(v.w) };
    ((ushort4v*)d)[off] = o;
}

// ---------------------------------------------------------------------------
// bf16 MFMA GEMM: C[m,n] = sum_k A[m,k]*B[n,k] + bias[n]; BMx128, 4 waves, BK=32
// MODE 0 (BM=128): QKV -> q_s/k_s/v_s bf16 [B,H,T,D] (coalesced)
// MODE 1 (BM=64): pos -> r bf16 [R,E];  MODE 2 (BM=64): out -> fp32
// ---------------------------------------------------------------------------
template<int MODE, int BM>
__global__ __launch_bounds__(256)
void gemm_bf16(const unsigned short* __restrict__ A, const unsigned short* __restrict__ B,
               const float* __restrict__ bias, void* __restrict__ out0,
               void* __restrict__ out1, void* __restrict__ out2, int K)
{
    constexpr int FM = BM / 32;
    __shared__ unsigned short As[BM * 36];
    __shared__ unsigned short Bs[128 * 36];
    const int bm  = blockIdx.y * BM;
    const int bn  = blockIdx.x * 128;
    const int tid = threadIdx.x;
    const int lane = tid & 63, w = tid >> 6;
    const int m16 = lane & 15, quad = lane >> 4;
    const int wm = (w & 1) * (BM / 2), wn = (w >> 1) * 64;

    floatx4 acc[FM][4];
    #pragma unroll
    for (int i = 0; i < FM; ++i)
        #pragma unroll
        for (int j = 0; j < 4; ++j) acc[i][j] = (floatx4){0.f, 0.f, 0.f, 0.f};

    for (int k0 = 0; k0 < K; k0 += 32) {
        #pragma unroll
        for (int s = tid; s < BM * 4; s += 256) {
            const int row = s >> 2, c = (s & 3) * 8;
            *(ushort8*)&As[row * 36 + c] = *(const ushort8*)(A + (size_t)(bm + row) * K + k0 + c);
        }
        #pragma unroll
        for (int s = tid; s < 512; s += 256) {
            const int row = s >> 2, c = (s & 3) * 8;
            *(ushort8*)&Bs[row * 36 + c] = *(const ushort8*)(B + (size_t)(bn + row) * K + k0 + c);
        }
        __syncthreads();
        short8 af[FM], bf[4];
        #pragma unroll
        for (int f = 0; f < FM; ++f) af[f] = ld16(&As[(wm + f * 16 + m16) * 36 + quad * 8]);
        #pragma unroll
        for (int f = 0; f < 4; ++f)  bf[f] = ld16(&Bs[(wn + f * 16 + m16) * 36 + quad * 8]);
        #pragma unroll
        for (int fm = 0; fm < FM; ++fm)
            #pragma unroll
            for (int fn = 0; fn < 4; ++fn)
                acc[fm][fn] = MFMA16(af[fm], bf[fn], acc[fm][fn]);
        __syncthreads();
    }

    #pragma unroll
    for (int fn = 0; fn < 4; ++fn) {
        const int n = bn + wn + fn * 16 + m16;
        const float bv = bias[n];
        #pragma unroll
        for (int fm = 0; fm < FM; ++fm) {
            #pragma unroll
            for (int rgi = 0; rgi < 4; ++rgi) {
                const int m = bm + wm + fm * 16 + quad * 4 + rgi;
                const float val = acc[fm][fn][rgi] + bv;
                if (MODE == 0) {
                    const int t = m >> 1, b = m & 1;
                    const int reg = n >> 9, c = n & 511, h = c >> 6, dd = c & 63;
                    unsigned short* dst = (unsigned short*)(reg == 0 ? out0 : (reg == 1 ? out1 : out2));
                    dst[((size_t)(b * HEADS + h) * T_SEQ + t) * DHEAD + dd] = f2b(val);
                } else if (MODE == 1) {
                    ((unsigned short*)out0)[(size_t)m * EMB + n] = f2b(val);
                } else {
                    ((float*)out0)[(size_t)m * EMB + n] = val;
                }
            }
        }
    }
}

// ---------------------------------------------------------------------------
// bf16 transpose: v_s [B,H,T,D] -> vT [B,H,D,T]
// ---------------------------------------------------------------------------
__global__ __launch_bounds__(256)
void transpose_v(const unsigned short* __restrict__ v_s, unsigned short* __restrict__ vT)
{
    __shared__ unsigned short tile[64 * 68];
    const int t0 = blockIdx.x * 64, bh = blockIdx.y;
    const int tid = threadIdx.x;
    const unsigned short* src = v_s + ((size_t)bh * T_SEQ + t0) * DHEAD;
    #pragma unroll
    for (int s = tid; s < 512; s += 256) {
        const int row = s >> 3, c = (s & 7) * 8;
        *(ushort8*)&tile[row * 68 + c] = *(const ushort8*)(src + row * DHEAD + c);
    }
    __syncthreads();
    unsigned short* dst = vT + (size_t)bh * DHEAD * T_SEQ + t0;
    #pragma unroll
    for (int s = tid; s < 512; s += 256) {
        const int d = s >> 3, c = (s & 7) * 8;
        ushort8 o;
        #pragma unroll
        for (int j = 0; j < 8; ++j) o[j] = tile[(c + j) * 68 + d];
        *(ushort8*)(dst + (size_t)d * T_SEQ + c) = o;
    }
}

// ---------------------------------------------------------------------------
// Split-s fused MFMA attention: double-buffered staging (2 barriers/tile),
// register prefetch pipeline, transposed ring with b64 writes, no-max exp2
// softmax, deferred l-reduction.
//   bd[t][s] = QR[t][T-1-t+s] (s<=t) | 0 (s==t+1) | QR[t+1][s-t-2] (s>=t+2)
// LDS (u16): k@0 (2x4608) v@9216 (2x4608) rp@18432 (2x4608)
//            ring@27648 [slot 0..127][i 0..63] stride 72. Total 72 KB -> 2/CU.
// NOTE: no arrays of LDS pointers (gfx950 addrspacecast static-init bug);
// buffer bases computed from parity index at each use.
// ---------------------------------------------------------------------------
__global__ __launch_bounds__(256)
void attn_mfma(const unsigned short* __restrict__ qg_, const unsigned short* __restrict__ kg_,
               const unsigned short* __restrict__ vtg_, const unsigned short* __restrict__ rg_,
               const float* __restrict__ rwb, const float* __restrict__ rrb,
               unsigned short* __restrict__ pO, float* __restrict__ pml)
{
    const int T   = T_SEQ;
    const int tb  = blockIdx.x;
    const int t0  = tb * 64;
    const int bh  = blockIdx.y;
    const int sp  = blockIdx.z;
    const int ss  = sp * (T / NSPLIT);
    const int ntiles = (T / NSPLIT) / 64;
    const int h   = bh & 7;
    const int tid = threadIdx.x;
    const int lane = tid & 63;
    const int w    = tid >> 6;
    const int m16  = lane & 15;
    const int quad = lane >> 4;
    const int ibase = 16 * w + quad * 4;

    __shared__ unsigned short lds[36864];
    unsigned short* ring  = lds + 27648;      // [slot][i], stride 72
    unsigned short* qrw_s = lds;              // pre-loop alias (k buf 0)
    unsigned short* qrr_s = lds + 9216;       // pre-loop alias (v buf 0)

    const unsigned short* qg  = qg_  + ((size_t)bh * T + t0) * DHEAD;
    const unsigned short* kg  = kg_  + (size_t)bh * T * DHEAD;
    const unsigned short* vtg = vtg_ + (size_t)bh * DHEAD * T;
    const unsigned short* rg  = rg_  + h * DHEAD;

    // ---- stage q tiles: (q + bias) * 0.125 * log2e ----
    const float QSCALE = 0.125f * 1.44269504089f;
    for (int idx = tid; idx < 65 * 16; idx += 256) {
        const int row = idx >> 4, c = (idx & 15) << 2;
        ushort4v qv = {0, 0, 0, 0};
        if (t0 + row < T) qv = *(const ushort4v*)(qg + row * DHEAD + c);
        const float4 rr = *(const float4*)(rrb + h * DHEAD + c);
        qrr_s[row * 72 + c + 0] = f2b((b2f(qv[0]) + rr.x) * QSCALE);
        qrr_s[row * 72 + c + 1] = f2b((b2f(qv[1]) + rr.y) * QSCALE);
        qrr_s[row * 72 + c + 2] = f2b((b2f(qv[2]) + rr.z) * QSCALE);
        qrr_s[row * 72 + c + 3] = f2b((b2f(qv[3]) + rr.w) * QSCALE);
        if (row < 64) {
            const float4 rw = *(const float4*)(rwb + h * DHEAD + c);
            qrw_s[row * 72 + c + 0] = f2b((b2f(qv[0]) + rw.x) * QSCALE);
            qrw_s[row * 72 + c + 1] = f2b((b2f(qv[1]) + rw.y) * QSCALE);
            qrw_s[row * 72 + c + 2] = f2b((b2f(qv[2]) + rw.z) * QSCALE);
            qrw_s[row * 72 + c + 3] = f2b((b2f(qv[3]) + rw.w) * QSCALE);
        }
    }
    __syncthreads();

    short8 a_ac[2], a_qrl[2], a_qru[2];
    {
        const unsigned short* p0 = &qrw_s[(16 * w + m16) * 72 + quad * 8];
        a_ac[0]  = ld16(p0);  a_ac[1]  = ld16(p0 + 32);
        const unsigned short* p1 = &qrr_s[(16 * w + m16) * 72 + quad * 8];
        a_qrl[0] = ld16(p1);  a_qrl[1] = ld16(p1 + 32);
        const unsigned short* p2 = &qrr_s[(16 * w + 1 + m16) * 72 + quad * 8];
        a_qru[0] = ld16(p2);  a_qru[1] = ld16(p2 + 32);
    }

    // per-thread (row, col) mapping for staging: 2 chunks of 512
    const int srow0 = tid >> 3,          scol0 = (tid & 7) * 8;
    const int srow1 = (tid + 256) >> 3,  scol1 = (tid & 7) * 8;

    ushort8 kr[2], vr[2], rr8[2];
    auto prefetch = [&](int s0n) {
        const bool ln = (s0n <= t0);
        const int jb = (ln ? (s0n + T - t0 - 64) : (s0n - t0 - 65)) + 64;
        int j0 = jb + srow0; j0 = j0 < 0 ? 0 : (j0 > T - 1 ? T - 1 : j0);
        int j1 = jb + srow1; j1 = j1 < 0 ? 0 : (j1 > T - 1 ? T - 1 : j1);
        kr[0]  = *(const ushort8*)(kg + (size_t)(s0n + srow0) * DHEAD + scol0);
        kr[1]  = *(const ushort8*)(kg + (size_t)(s0n + srow1) * DHEAD + scol1);
        vr[0]  = *(const ushort8*)(vtg + (size_t)srow0 * T + s0n + scol0);
        vr[1]  = *(const ushort8*)(vtg + (size_t)srow1 * T + s0n + scol1);
        rr8[0] = *(const ushort8*)(rg + (size_t)j0 * EMB + scol0);
        rr8[1] = *(const ushort8*)(rg + (size_t)j1 * EMB + scol1);
    };
    auto store_bufs = [&](int q) {
        unsigned short* kb = lds + q * 4608;
        unsigned short* vb = lds + 9216 + q * 4608;
        unsigned short* rb = lds + 18432 + q * 4608;
        *(ushort8*)&kb[srow0 * 72 + scol0] = kr[0];
        *(ushort8*)&kb[srow1 * 72 + scol1] = kr[1];
        *(ushort8*)&vb[srow0 * 72 + scol0] = vr[0];
        *(ushort8*)&vb[srow1 * 72 + scol1] = vr[1];
        *(ushort8*)&rb[srow0 * 72 + scol0] = rr8[0];
        *(ushort8*)&rb[srow1 * 72 + scol1] = rr8[1];
    };
    auto stage_to = [&](unsigned short* dstb, int jbase) {
        #pragma unroll
        for (int idx = tid; idx < 512; idx += 256) {
            const int row = idx >> 3, c = (idx & 7) * 8;
            int j = jbase + row; j = j < 0 ? 0 : (j > T - 1 ? T - 1 : j);
            *(ushort8*)&dstb[row * 72 + c] = *(const ushort8*)(rg + (size_t)j * EMB + c);
        }
    };
    auto qr_half = [&](const unsigned short* rsb, const short8* aq, int slotbase) {
        #pragma unroll
        for (int cc = 0; cc < 4; ++cc) {
            floatx4 q4 = (floatx4){0.f, 0.f, 0.f, 0.f};
            #pragma unroll
            for (int ks = 0; ks < 2; ++ks) {
                short8 bfr = ld16(&rsb[(16 * cc + m16) * 72 + ks * 32 + quad * 8]);
                q4 = MFMA16(aq[ks], bfr, q4);
            }
            ushort4v o = { f2bt(q4[0]), f2bt(q4[1]), f2bt(q4[2]), f2bt(q4[3]) };
            *(ushort4v*)&ring[(slotbase + 16 * cc + m16) * 72 + ibase] = o;   // b64
        }
    };

    floatx4 O[4];
    float lrun[4];
    #pragma unroll
    for (int ct = 0; ct < 4; ++ct) O[ct] = (floatx4){0.f, 0.f, 0.f, 0.f};
    #pragma unroll
    for (int rgi = 0; rgi < 4; ++rgi) lrun[rgi] = 0.f;

    // ---- prologue ----
    {
        const bool startLower = (ss <= t0);
        const int wstart0 = startLower ? (ss + T - t0 - 64) : (ss - t0 - 65);
        const int nph0 = startLower ? (ss >> 6) : 0;
        stage_to(lds + 18432 + 4608, wstart0);   // prologue r -> rp buf 1
        prefetch(ss);                            // tile 0 -> regs
        __syncthreads();
        qr_half(lds + 18432 + 4608, startLower ? a_qrl : a_qru, (nph0 & 1) * 64);
        store_bufs(0);                           // tile 0 staging (clobbers q alias)
        __syncthreads();                         // B2(pre)
    }

    for (int na = 0; na < ntiles; ++na) {
        const int s0 = ss + na * 64;
        const int p = na & 1;
        unsigned short* kb = lds + p * 4608;
        unsigned short* vb = lds + 9216 + p * 4608;
        unsigned short* rp = lds + 18432 + p * 4608;
        const bool lower = (s0 <= t0);
        const int nph    = lower ? (s0 >> 6) : ((s0 - t0) >> 6);
        const int rbase  = (nph & 1) * 64;
        const int wbase  = 64 - rbase;
        const bool hasNext = (na + 1 < ntiles);

        // ---- phase A: AC + QR (+ issue next-tile prefetch) ----
        floatx4 acf[4];
        #pragma unroll
        for (int ct = 0; ct < 4; ++ct) {
            acf[ct] = (floatx4){0.f, 0.f, 0.f, 0.f};
            #pragma unroll
            for (int ks = 0; ks < 2; ++ks) {
                short8 bfr = ld16(&kb[(16 * ct + m16) * 72 + ks * 32 + quad * 8]);
                acf[ct] = MFMA16(a_ac[ks], bfr, acf[ct]);
            }
        }
        qr_half(rp, lower ? a_qrl : a_qru, wbase);
        if (hasNext) prefetch(s0 + 64);
        __syncthreads();                       // B1

        // ---- phase B: assemble + softmax + P write + staging store ----
        if (s0 != t0) {
            #pragma unroll
            for (int ct = 0; ct < 4; ++ct) {
                #pragma unroll
                for (int rgi = 0; rgi < 4; ++rgi) {
                    const int i = ibase + rgi;
                    const int slot = ((63 - i + 16 * ct + m16) + rbase) & 127;
                    acf[ct][rgi] += b2f(ring[slot * 72 + i]);
                }
            }
            if (s0 == t0 + 64 && lane == 48 && w == 3)
                acf[0][3] -= b2f(ring[rbase * 72 + 63]);
        } else {
            // DIAG pass 1: lower-masked
            #pragma unroll
            for (int ct = 0; ct < 4; ++ct) {
                #pragma unroll
                for (int rgi = 0; rgi < 4; ++rgi) {
                    const int i = ibase + rgi, u = 16 * ct + m16;
                    if (u <= i) acf[ct][rgi] += b2f(ring[(((63 - i + u) + rbase) & 127) * 72 + i]);
                }
            }
            // DIAG pass 2: upper prologue into rp[1-p] + ring slots 64..127
            unsigned short* rpo = lds + 18432 + (1 - p) * 4608;
            __syncthreads();                   // Bd1
            stage_to(rpo, -1);
            __syncthreads();                   // Bd2
            qr_half(rpo, a_qru, 64);
            __syncthreads();                   // Bd3
            #pragma unroll
            for (int ct = 0; ct < 4; ++ct) {
                #pragma unroll
                for (int rgi = 0; rgi < 4; ++rgi) {
                    const int i = ibase + rgi, u = 16 * ct + m16;
                    if (u >= i + 2) acf[ct][rgi] += b2f(ring[(63 - i + u) * 72 + i]);
                }
            }
        }

        // no-max exp2 softmax, per-lane l accumulation
        #pragma unroll
        for (int rgi = 0; rgi < 4; ++rgi) {
            #pragma unroll
            for (int ct = 0; ct < 4; ++ct) {
                const float pv = exp2f(acf[ct][rgi]);
                acf[ct][rgi] = pv;
                lrun[rgi] += pv;
            }
        }
        // P -> rp (r reads done at B1)
        #pragma unroll
        for (int ct = 0; ct < 4; ++ct)
            #pragma unroll
            for (int rgi = 0; rgi < 4; ++rgi)
                rp[(ibase + rgi) * 72 + 16 * ct + m16] = f2bt(acf[ct][rgi]);
        if (hasNext) store_bufs(1 - p);
        __syncthreads();                       // B2

        // ---- PV ----
        short8 ap[2];
        {
            const unsigned short* pp = &rp[(16 * w + m16) * 72 + quad * 8];
            ap[0] = ld16(pp); ap[1] = ld16(pp + 32);
        }
        #pragma unroll
        for (int ct = 0; ct < 4; ++ct) {
            #pragma unroll
            for (int ks = 0; ks < 2; ++ks) {
                short8 bfr = ld16(&vb[(16 * ct + m16) * 72 + ks * 32 + quad * 8]);
                O[ct] = MFMA16(ap[ks], bfr, O[ct]);
            }
        }
    }

    // ---- epilogue ----
    unsigned short* po = pO + (((size_t)sp * 16 + bh) * 32 + tb) * 4096;
    float* ml          = pml + (((size_t)sp * 16 + bh) * 32 + tb) * 64;
    #pragma unroll
    for (int rgi = 0; rgi < 4; ++rgi) {
        float l = lrun[rgi];
        #pragma unroll
        for (int off = 1; off < 16; off <<= 1)
            l += __shfl_xor(l, off);
        const int i = ibase + rgi;
        #pragma unroll
        for (int ct = 0; ct < 4; ++ct)
            po[i * 64 + 16 * ct + m16] = f2bt(O[ct][rgi]);
        if (m16 == 0) ml[i] = l;
    }
}

// ---------------------------------------------------------------------------
// Merge NSPLIT partials -> ctx bf16 [T,B,E]
// ---------------------------------------------------------------------------
__global__ __launch_bounds__(256)
void merge_attn(const unsigned short* __restrict__ pO, const float* __restrict__ pml,
                unsigned short* __restrict__ ctx)
{
    const int tb = blockIdx.x, bh = blockIdx.y;
    const int h = bh & 7, b = bh >> 3;
    const int tid = threadIdx.x;
    const int row = tid >> 2, cseg = (tid & 3) * 16;

    const size_t blk0 = (((size_t)0 * 16 + bh) * 32 + tb);
    const size_t blk1 = (((size_t)1 * 16 + bh) * 32 + tb);
    const float inv = 1.f / (pml[blk0 * 64 + row] + pml[blk1 * 64 + row]);

    const unsigned short* o0 = pO + blk0 * 4096 + row * 64 + cseg;
    const unsigned short* o1 = pO + blk1 * 4096 + row * 64 + cseg;
    unsigned short* dst = ctx + ((size_t)(tb * 64 + row) * BATCH + b) * EMB + h * 64 + cseg;
    ushort8 a0 = *(const ushort8*)o0, a1 = *(const ushort8*)o1;
    ushort8 b0 = *(const ushort8*)(o0 + 8), b1 = *(const ushort8*)(o1 + 8);
    ushort8 r0, r1;
    #pragma unroll
    for (int j = 0; j < 8; ++j) {
        r0[j] = f2b((b2f(a0[j]) + b2f(a1[j])) * inv);
        r1[j] = f2b((b2f(b0[j]) + b2f(b1[j])) * inv);
    }
    *(ushort8*)dst = r0;
    *(ushort8*)(dst + 8) = r1;
}

// ---------------------------------------------------------------------------
// Workspace (ushort offsets), 15,990,784 ush = 31.98 MB:
//   0        inb     2,097,152  \ dead after GEMMs -> pO bf16 overlay @0
//   2097152  posb    1,048,576   |
//   3145728  w_inb     786,432   |
//   3932160  w_posb    262,144  /
//   4194304  v_s     2,097,152  (dead after transpose) -> pml fp32 overlay
//   6291456  w_outb    262,144
//   6553600  q_s     2,097,152
//   8650752  k_s     2,097,152
//   10747904 vT      2,097,152
//   12845056 r_b     1,048,576
//   13893632 ctx_b   2,097,152
// ---------------------------------------------------------------------------
extern "C" void kernel_launch(void* const* d_in, const int* in_sizes, int n_in,
                              void* d_out, int out_size, void* d_ws, size_t ws_size,
                              hipStream_t stream)
{
    const float* input = (const float*)d_in[0];
    const float* pos   = (const float*)d_in[1];
    const float* w_in  = (const float*)d_in[2];
    const float* w_out = (const float*)d_in[3];
    const float* w_pos = (const float*)d_in[4];
    const float* b_in  = (const float*)d_in[5];
    const float* b_out = (const float*)d_in[6];
    const float* b_pos = (const float*)d_in[7];
    const float* rwb   = (const float*)d_in[8];
    const float* rrb   = (const float*)d_in[9];

    unsigned short* ws     = (unsigned short*)d_ws;
    unsigned short* inb    = ws;
    unsigned short* posb   = ws + 2097152;
    unsigned short* w_inb  = ws + 3145728;
    unsigned short* w_posb = ws + 3932160;
    unsigned short* v_s    = ws + 4194304;
    unsigned short* w_outb = ws + 6291456;
    unsigned short* q_s    = ws + 6553600;
    unsigned short* k_s    = ws + 8650752;
    unsigned short* vT     = ws + 10747904;
    unsigned short* r_b    = ws + 12845056;
    unsigned short* ctx_b  = ws + 13893632;
    unsigned short* pO     = ws;                       // overlay
    float*          pml    = (float*)(ws + 4194304);   // overlay (v_s dead)

    cvt_all<<<4352, 256, 0, stream>>>(input, pos, w_in, w_pos, w_out,
                                      inb, posb, w_inb, w_posb, w_outb);
    gemm_bf16<0, 128><<<dim3(12, 32), 256, 0, stream>>>(inb, w_inb, b_in, q_s, k_s, v_s, EMB);
    gemm_bf16<1, 64><<<dim3(4, 32), 256, 0, stream>>>(posb, w_posb, b_pos, r_b, nullptr, nullptr, EMB);
    transpose_v<<<dim3(32, 16), 256, 0, stream>>>(v_s, vT);
    attn_mfma<<<dim3(32, 16, NSPLIT), 256, 0, stream>>>(q_s, k_s, vT, r_b, rwb, rrb, pO, pml);
    merge_attn<<<dim3(32, 16), 256, 0, stream>>>(pO, pml, ctx_b);
    gemm_bf16<2, 64><<<dim3(4, 64), 256, 0, stream>>>(ctx_b, w_outb, b_out, d_out, nullptr, nullptr, EMB);
}

// Round 10
// 218.801 us; speedup vs baseline: 1.4282x; 1.2067x over previous
//
#include <hip/hip_runtime.h>

#define T_SEQ 2048
#define BATCH 2
#define HEADS 8
#define DHEAD 64
#define EMB   512

typedef __attribute__((ext_vector_type(8))) short short8;
typedef __attribute__((ext_vector_type(4))) float floatx4;
typedef __attribute__((ext_vector_type(8))) unsigned short ushort8;
typedef __attribute__((ext_vector_type(4))) unsigned short ushort4v;

// RNE convert (cold paths)
__device__ __forceinline__ unsigned short f2b(float f) {
    union { float f; unsigned u; } v; v.f = f;
    unsigned r = v.u + 0x7fffu + ((v.u >> 16) & 1u);
    return (unsigned short)(r >> 16);
}
// 1-op truncating convert (hot paths)
__device__ __forceinline__ unsigned short f2bt(float f) {
    union { float f; unsigned u; } v; v.f = f;
    return (unsigned short)(v.u >> 16);
}
__device__ __forceinline__ float b2f(unsigned short s) {
    union { unsigned u; float f; } v; v.u = ((unsigned)s) << 16; return v.f;
}
// 8-B-aligned LDS fragment load as two b64s (works for stride-68 rows)
__device__ __forceinline__ short8 ld_frag(const unsigned short* p) {
    ushort4v lo = *(const ushort4v*)p;
    ushort4v hi = *(const ushort4v*)(p + 4);
    short8 r;
    r[0] = lo[0]; r[1] = lo[1]; r[2] = lo[2]; r[3] = lo[3];
    r[4] = hi[0]; r[5] = hi[1]; r[6] = hi[2]; r[7] = hi[3];
    return r;
}
__device__ __forceinline__ void st8(unsigned short* p, ushort8 v) {
    ushort4v lo = { v[0], v[1], v[2], v[3] };
    ushort4v hi = { v[4], v[5], v[6], v[7] };
    *(ushort4v*)p = lo;
    *(ushort4v*)(p + 4) = hi;
}
#define MFMA16(a, b, c) __builtin_amdgcn_mfma_f32_16x16x32_bf16(a, b, c, 0, 0, 0)

// ---------------------------------------------------------------------------
// One-shot fp32 -> bf16 conversion of all 5 tensors.
// ---------------------------------------------------------------------------
__global__ __launch_bounds__(256)
void cvt_all(const float* __restrict__ s0, const float* __restrict__ s1,
             const float* __restrict__ s2, const float* __restrict__ s3,
             const float* __restrict__ s4,
             unsigned short* __restrict__ d0, unsigned short* __restrict__ d1,
             unsigned short* __restrict__ d2, unsigned short* __restrict__ d3,
             unsigned short* __restrict__ d4)
{
    const int i = blockIdx.x * 256 + threadIdx.x;
    const float* s; unsigned short* d; int off;
    if      (i <  524288) { s = s0; d = d0; off = i; }
    else if (i <  786432) { s = s1; d = d1; off = i -  524288; }
    else if (i <  983040) { s = s2; d = d2; off = i -  786432; }
    else if (i < 1048576) { s = s3; d = d3; off = i -  983040; }
    else if (i < 1114112) { s = s4; d = d4; off = i - 1048576; }
    else return;
    const float4 v = ((const float4*)s)[off];
    ushort4v o = { f2b(v.x), f2b(v.y), f2b(v.z), f2b(v.w) };
    ((ushort4v*)d)[off] = o;
}

// ---------------------------------------------------------------------------
// bf16 MFMA GEMM: C[m,n] = sum_k A[m,k]*B[n,k] + bias[n]; 128x128, 4 waves, BK=32
// MODE 0: QKV -> q_s/k_s/v_s bf16 [B,H,T,D] (coalesced)
// MODE 1: pos -> r bf16 [R,E];  MODE 2: out -> fp32
// ---------------------------------------------------------------------------
template<int MODE>
__global__ __launch_bounds__(256)
void gemm_bf16(const unsigned short* __restrict__ A, const unsigned short* __restrict__ B,
               const float* __restrict__ bias, void* __restrict__ out0,
               void* __restrict__ out1, void* __restrict__ out2, int K)
{
    __shared__ unsigned short As[128 * 36];
    __shared__ unsigned short Bs[128 * 36];
    const int bm  = blockIdx.y * 128;
    const int bn  = blockIdx.x * 128;
    const int tid = threadIdx.x;
    const int lane = tid & 63, w = tid >> 6;
    const int m16 = lane & 15, quad = lane >> 4;
    const int wm = (w & 1) * 64, wn = (w >> 1) * 64;

    floatx4 acc[4][4];
    #pragma unroll
    for (int i = 0; i < 4; ++i)
        #pragma unroll
        for (int j = 0; j < 4; ++j) acc[i][j] = (floatx4){0.f, 0.f, 0.f, 0.f};

    for (int k0 = 0; k0 < K; k0 += 32) {
        #pragma unroll
        for (int s = tid; s < 512; s += 256) {
            const int row = s >> 2, c = (s & 3) * 8;
            *(ushort8*)&As[row * 36 + c] = *(const ushort8*)(A + (size_t)(bm + row) * K + k0 + c);
            *(ushort8*)&Bs[row * 36 + c] = *(const ushort8*)(B + (size_t)(bn + row) * K + k0 + c);
        }
        __syncthreads();
        short8 af[4], bf[4];
        #pragma unroll
        for (int f = 0; f < 4; ++f) {
            af[f] = ld_frag(&As[(wm + f * 16 + m16) * 36 + quad * 8]);
            bf[f] = ld_frag(&Bs[(wn + f * 16 + m16) * 36 + quad * 8]);
        }
        #pragma unroll
        for (int fm = 0; fm < 4; ++fm)
            #pragma unroll
            for (int fn = 0; fn < 4; ++fn)
                acc[fm][fn] = MFMA16(af[fm], bf[fn], acc[fm][fn]);
        __syncthreads();
    }

    #pragma unroll
    for (int fn = 0; fn < 4; ++fn) {
        const int n = bn + wn + fn * 16 + m16;
        const float bv = bias[n];
        #pragma unroll
        for (int fm = 0; fm < 4; ++fm) {
            #pragma unroll
            for (int rgi = 0; rgi < 4; ++rgi) {
                const int m = bm + wm + fm * 16 + quad * 4 + rgi;
                const float val = acc[fm][fn][rgi] + bv;
                if (MODE == 0) {
                    const int t = m >> 1, b = m & 1;
                    const int reg = n >> 9, c = n & 511, h = c >> 6, dd = c & 63;
                    unsigned short* dst = (unsigned short*)(reg == 0 ? out0 : (reg == 1 ? out1 : out2));
                    dst[((size_t)(b * HEADS + h) * T_SEQ + t) * DHEAD + dd] = f2b(val);
                } else if (MODE == 1) {
                    ((unsigned short*)out0)[(size_t)m * EMB + n] = f2b(val);
                } else {
                    ((float*)out0)[(size_t)m * EMB + n] = val;
                }
            }
        }
    }
}

// ---------------------------------------------------------------------------
// bf16 transpose: v_s [B,H,T,D] -> vT [B,H,D,T]
// ---------------------------------------------------------------------------
__global__ __launch_bounds__(256)
void transpose_v(const unsigned short* __restrict__ v_s, unsigned short* __restrict__ vT)
{
    __shared__ unsigned short tile[64 * 68];
    const int t0 = blockIdx.x * 64, bh = blockIdx.y;
    const int tid = threadIdx.x;
    const unsigned short* src = v_s + ((size_t)bh * T_SEQ + t0) * DHEAD;
    #pragma unroll
    for (int s = tid; s < 512; s += 256) {
        const int row = s >> 3, c = (s & 7) * 8;
        st8(&tile[row * 68 + c], *(const ushort8*)(src + row * DHEAD + c));
    }
    __syncthreads();
    unsigned short* dst = vT + (size_t)bh * DHEAD * T_SEQ + t0;
    #pragma unroll
    for (int s = tid; s < 512; s += 256) {
        const int d = s >> 3, c = (s & 7) * 8;
        ushort8 o;
        #pragma unroll
        for (int j = 0; j < 8; ++j) o[j] = tile[(c + j) * 68 + d];
        *(ushort8*)(dst + (size_t)d * T_SEQ + c) = o;
    }
}

// ---------------------------------------------------------------------------
// Fused MFMA attention (full s-range per block): double-buffered staging
// (2 barriers/tile), register prefetch, [i][slot] ring (stride 133, scalar
// writes), stride-68 buffers, no-max exp2 softmax, deferred l-reduction.
//   bd[t][s] = QR[t][T-1-t+s] (s<=t) | 0 (s==t+1) | QR[t+1][s-t-2] (s>=t+2)
// LDS (u16): k@0 (2x4352) v@8704 (2x4352) rp@17408 (2x4352) ring@26112
// (64x133). Total 69,248 B -> 2 blocks/CU.
// No arrays of LDS pointers (gfx950 addrspacecast static-init bug).
// ---------------------------------------------------------------------------
__global__ __launch_bounds__(256)
void attn_mfma(const unsigned short* __restrict__ qg_, const unsigned short* __restrict__ kg_,
               const unsigned short* __restrict__ vtg_, const unsigned short* __restrict__ rg_,
               const float* __restrict__ rwb, const float* __restrict__ rrb,
               unsigned short* __restrict__ ctx)
{
    const int T   = T_SEQ;
    const int tb  = blockIdx.x;
    const int t0  = tb * 64;
    const int bh  = blockIdx.y;
    const int h   = bh & 7;
    const int b   = bh >> 3;
    const int tid = threadIdx.x;
    const int lane = tid & 63;
    const int w    = tid >> 6;
    const int m16  = lane & 15;
    const int quad = lane >> 4;
    const int ibase = 16 * w + quad * 4;

    __shared__ unsigned short lds[34624];
    unsigned short* ring  = lds + 26112;     // [i][slot], stride 133
    unsigned short* qrw_s = lds;             // pre-loop alias (k buf 0)
    unsigned short* qrr_s = lds + 8704;      // pre-loop alias (v buf 0, 65 rows)

    const unsigned short* qg  = qg_  + ((size_t)bh * T + t0) * DHEAD;
    const unsigned short* kg  = kg_  + (size_t)bh * T * DHEAD;
    const unsigned short* vtg = vtg_ + (size_t)bh * DHEAD * T;
    const unsigned short* rg  = rg_  + h * DHEAD;

    // ---- stage q tiles: (q + bias) * 0.125 * log2e ----
    const float QSCALE = 0.125f * 1.44269504089f;
    for (int idx = tid; idx < 65 * 16; idx += 256) {
        const int row = idx >> 4, c = (idx & 15) << 2;
        ushort4v qv = {0, 0, 0, 0};
        if (t0 + row < T) qv = *(const ushort4v*)(qg + row * DHEAD + c);
        const float4 rr = *(const float4*)(rrb + h * DHEAD + c);
        qrr_s[row * 68 + c + 0] = f2b((b2f(qv[0]) + rr.x) * QSCALE);
        qrr_s[row * 68 + c + 1] = f2b((b2f(qv[1]) + rr.y) * QSCALE);
        qrr_s[row * 68 + c + 2] = f2b((b2f(qv[2]) + rr.z) * QSCALE);
        qrr_s[row * 68 + c + 3] = f2b((b2f(qv[3]) + rr.w) * QSCALE);
        if (row < 64) {
            const float4 rw = *(const float4*)(rwb + h * DHEAD + c);
            qrw_s[row * 68 + c + 0] = f2b((b2f(qv[0]) + rw.x) * QSCALE);
            qrw_s[row * 68 + c + 1] = f2b((b2f(qv[1]) + rw.y) * QSCALE);
            qrw_s[row * 68 + c + 2] = f2b((b2f(qv[2]) + rw.z) * QSCALE);
            qrw_s[row * 68 + c + 3] = f2b((b2f(qv[3]) + rw.w) * QSCALE);
        }
    }
    __syncthreads();

    short8 a_ac[2], a_qrl[2], a_qru[2];
    {
        const unsigned short* p0 = &qrw_s[(16 * w + m16) * 68 + quad * 8];
        a_ac[0]  = ld_frag(p0);  a_ac[1]  = ld_frag(p0 + 32);
        const unsigned short* p1 = &qrr_s[(16 * w + m16) * 68 + quad * 8];
        a_qrl[0] = ld_frag(p1);  a_qrl[1] = ld_frag(p1 + 32);
        const unsigned short* p2 = &qrr_s[(16 * w + 1 + m16) * 68 + quad * 8];
        a_qru[0] = ld_frag(p2);  a_qru[1] = ld_frag(p2 + 32);
    }

    // per-thread (row, col) mapping for staging: 2 chunks of 512
    const int srow0 = tid >> 3,          scol0 = (tid & 7) * 8;
    const int srow1 = (tid + 256) >> 3,  scol1 = (tid & 7) * 8;

    ushort8 kr[2], vr[2], rr8[2];
    auto prefetch = [&](int s0n) {
        const bool ln = (s0n <= t0);
        const int jb = (ln ? (s0n + T - t0 - 64) : (s0n - t0 - 65)) + 64;
        int j0 = jb + srow0; j0 = j0 < 0 ? 0 : (j0 > T - 1 ? T - 1 : j0);
        int j1 = jb + srow1; j1 = j1 < 0 ? 0 : (j1 > T - 1 ? T - 1 : j1);
        kr[0]  = *(const ushort8*)(kg + (size_t)(s0n + srow0) * DHEAD + scol0);
        kr[1]  = *(const ushort8*)(kg + (size_t)(s0n + srow1) * DHEAD + scol1);
        vr[0]  = *(const ushort8*)(vtg + (size_t)srow0 * T + s0n + scol0);
        vr[1]  = *(const ushort8*)(vtg + (size_t)srow1 * T + s0n + scol1);
        rr8[0] = *(const ushort8*)(rg + (size_t)j0 * EMB + scol0);
        rr8[1] = *(const ushort8*)(rg + (size_t)j1 * EMB + scol1);
    };
    auto store_bufs = [&](int q) {
        unsigned short* kb = lds + q * 4352;
        unsigned short* vb = lds + 8704 + q * 4352;
        unsigned short* rb = lds + 17408 + q * 4352;
        st8(&kb[srow0 * 68 + scol0], kr[0]);
        st8(&kb[srow1 * 68 + scol1], kr[1]);
        st8(&vb[srow0 * 68 + scol0], vr[0]);
        st8(&vb[srow1 * 68 + scol1], vr[1]);
        st8(&rb[srow0 * 68 + scol0], rr8[0]);
        st8(&rb[srow1 * 68 + scol1], rr8[1]);
    };
    auto stage_to = [&](unsigned short* dstb, int jbase) {
        #pragma unroll
        for (int idx = tid; idx < 512; idx += 256) {
            const int row = idx >> 3, c = (idx & 7) * 8;
            int j = jbase + row; j = j < 0 ? 0 : (j > T - 1 ? T - 1 : j);
            st8(&dstb[row * 68 + c], *(const ushort8*)(rg + (size_t)j * EMB + c));
        }
    };
    auto qr_half = [&](const unsigned short* rsb, const short8* aq, int slotbase) {
        #pragma unroll
        for (int cc = 0; cc < 4; ++cc) {
            floatx4 q4 = (floatx4){0.f, 0.f, 0.f, 0.f};
            #pragma unroll
            for (int ks = 0; ks < 2; ++ks) {
                short8 bfr = ld_frag(&rsb[(16 * cc + m16) * 68 + ks * 32 + quad * 8]);
                q4 = MFMA16(aq[ks], bfr, q4);
            }
            #pragma unroll
            for (int rgi = 0; rgi < 4; ++rgi)
                ring[(ibase + rgi) * 133 + slotbase + 16 * cc + m16] = f2bt(q4[rgi]);
        }
    };

    floatx4 O[4];
    float lrun[4];
    #pragma unroll
    for (int ct = 0; ct < 4; ++ct) O[ct] = (floatx4){0.f, 0.f, 0.f, 0.f};
    #pragma unroll
    for (int rgi = 0; rgi < 4; ++rgi) lrun[rgi] = 0.f;

    // ---- prologue: lower window cols 0..63 (all blocks start lower at s0=0) ----
    {
        stage_to(lds + 17408 + 4352, T - t0 - 64);   // prologue r -> rp buf 1
        prefetch(0);                                  // tile 0 -> regs
        __syncthreads();
        qr_half(lds + 17408 + 4352, a_qrl, 0);
        store_bufs(0);                                // clobbers q aliases (reads done)
        __syncthreads();
    }

    for (int na = 0; na < T / 64; ++na) {
        const int s0 = na * 64;
        const int p = na & 1;
        unsigned short* kb = lds + p * 4352;
        unsigned short* vb = lds + 8704 + p * 4352;
        unsigned short* rp = lds + 17408 + p * 4352;
        const bool lower = (s0 <= t0);
        const int nph    = lower ? (s0 >> 6) : ((s0 - t0) >> 6);
        const int rbase  = (nph & 1) * 64;
        const int wbase  = 64 - rbase;
        const bool hasNext = (na + 1 < T / 64);

        // ---- phase A: AC + QR (+ issue next-tile prefetch) ----
        floatx4 acf[4];
        #pragma unroll
        for (int ct = 0; ct < 4; ++ct) {
            acf[ct] = (floatx4){0.f, 0.f, 0.f, 0.f};
            #pragma unroll
            for (int ks = 0; ks < 2; ++ks) {
                short8 bfr = ld_frag(&kb[(16 * ct + m16) * 68 + ks * 32 + quad * 8]);
                acf[ct] = MFMA16(a_ac[ks], bfr, acf[ct]);
            }
        }
        qr_half(rp, lower ? a_qrl : a_qru, wbase);
        if (hasNext) prefetch(s0 + 64);
        __syncthreads();                       // B1

        // ---- phase B: assemble + softmax + P write + staging store ----
        if (s0 != t0) {
            #pragma unroll
            for (int ct = 0; ct < 4; ++ct) {
                #pragma unroll
                for (int rgi = 0; rgi < 4; ++rgi) {
                    const int i = ibase + rgi;
                    const int slot = ((63 - i + 16 * ct + m16) + rbase) & 127;
                    acf[ct][rgi] += b2f(ring[i * 133 + slot]);
                }
            }
            if (s0 == t0 + 64 && lane == 48 && w == 3)
                acf[0][3] -= b2f(ring[63 * 133 + (rbase & 127)]);
        } else {
            // DIAG pass 1: lower-masked
            #pragma unroll
            for (int ct = 0; ct < 4; ++ct) {
                #pragma unroll
                for (int rgi = 0; rgi < 4; ++rgi) {
                    const int i = ibase + rgi, u = 16 * ct + m16;
                    if (u <= i) acf[ct][rgi] += b2f(ring[i * 133 + (((63 - i + u) + rbase) & 127)]);
                }
            }
            // DIAG pass 2: upper prologue into rp[1-p] + ring slots 64..127
            unsigned short* rpo = lds + 17408 + (1 - p) * 4352;
            __syncthreads();                   // Bd1
            stage_to(rpo, -1);
            __syncthreads();                   // Bd2
            qr_half(rpo, a_qru, 64);
            __syncthreads();                   // Bd3
            #pragma unroll
            for (int ct = 0; ct < 4; ++ct) {
                #pragma unroll
                for (int rgi = 0; rgi < 4; ++rgi) {
                    const int i = ibase + rgi, u = 16 * ct + m16;
                    if (u >= i + 2) acf[ct][rgi] += b2f(ring[i * 133 + 63 - i + u]);
                }
            }
        }

        // no-max exp2 softmax, per-lane l accumulation
        #pragma unroll
        for (int rgi = 0; rgi < 4; ++rgi) {
            #pragma unroll
            for (int ct = 0; ct < 4; ++ct) {
                const float pv = exp2f(acf[ct][rgi]);
                acf[ct][rgi] = pv;
                lrun[rgi] += pv;
            }
        }
        // P -> rp (r reads done at B1)
        #pragma unroll
        for (int ct = 0; ct < 4; ++ct)
            #pragma unroll
            for (int rgi = 0; rgi < 4; ++rgi)
                rp[(ibase + rgi) * 68 + 16 * ct + m16] = f2bt(acf[ct][rgi]);
        if (hasNext) store_bufs(1 - p);
        __syncthreads();                       // B2

        // ---- PV ----
        short8 ap[2];
        {
            const unsigned short* pp = &rp[(16 * w + m16) * 68 + quad * 8];
            ap[0] = ld_frag(pp); ap[1] = ld_frag(pp + 32);
        }
        #pragma unroll
        for (int ct = 0; ct < 4; ++ct) {
            #pragma unroll
            for (int ks = 0; ks < 2; ++ks) {
                short8 bfr = ld_frag(&vb[(16 * ct + m16) * 68 + ks * 32 + quad * 8]);
                O[ct] = MFMA16(ap[ks], bfr, O[ct]);
            }
        }
    }

    // ---- epilogue: reduce l, write normalized ctx bf16 [T,B,E] ----
    #pragma unroll
    for (int rgi = 0; rgi < 4; ++rgi) {
        float l = lrun[rgi];
        #pragma unroll
        for (int off = 1; off < 16; off <<= 1)
            l += __shfl_xor(l, off);
        const float inv = 1.f / l;
        const int t = t0 + ibase + rgi;
        #pragma unroll
        for (int ct = 0; ct < 4; ++ct)
            ctx[((size_t)t * BATCH + b) * EMB + h * DHEAD + 16 * ct + m16] = f2bt(O[ct][rgi] * inv);
    }
}

// ---------------------------------------------------------------------------
// Workspace (ushort offsets), 15,990,784 ush = 31.98 MB:
//   0        inb     2,097,152
//   2097152  posb    1,048,576
//   3145728  w_inb     786,432
//   3932160  w_posb    262,144
//   4194304  v_s     2,097,152
//   6291456  w_outb    262,144
//   6553600  q_s     2,097,152
//   8650752  k_s     2,097,152
//   10747904 vT      2,097,152
//   12845056 r_b     1,048,576
//   13893632 ctx_b   2,097,152
// ---------------------------------------------------------------------------
extern "C" void kernel_launch(void* const* d_in, const int* in_sizes, int n_in,
                              void* d_out, int out_size, void* d_ws, size_t ws_size,
                              hipStream_t stream)
{
    const float* input = (const float*)d_in[0];
    const float* pos   = (const float*)d_in[1];
    const float* w_in  = (const float*)d_in[2];
    const float* w_out = (const float*)d_in[3];
    const float* w_pos = (const float*)d_in[4];
    const float* b_in  = (const float*)d_in[5];
    const float* b_out = (const float*)d_in[6];
    const float* b_pos = (const float*)d_in[7];
    const float* rwb   = (const float*)d_in[8];
    const float* rrb   = (const float*)d_in[9];

    unsigned short* ws     = (unsigned short*)d_ws;
    unsigned short* inb    = ws;
    unsigned short* posb   = ws + 2097152;
    unsigned short* w_inb  = ws + 3145728;
    unsigned short* w_posb = ws + 3932160;
    unsigned short* v_s    = ws + 4194304;
    unsigned short* w_outb = ws + 6291456;
    unsigned short* q_s    = ws + 6553600;
    unsigned short* k_s    = ws + 8650752;
    unsigned short* vT     = ws + 10747904;
    unsigned short* r_b    = ws + 12845056;
    unsigned short* ctx_b  = ws + 13893632;

    cvt_all<<<4352, 256, 0, stream>>>(input, pos, w_in, w_pos, w_out,
                                      inb, posb, w_inb, w_posb, w_outb);
    gemm_bf16<0><<<dim3(12, 32), 256, 0, stream>>>(inb, w_inb, b_in, q_s, k_s, v_s, EMB);
    gemm_bf16<1><<<dim3(4, 16), 256, 0, stream>>>(posb, w_posb, b_pos, r_b, nullptr, nullptr, EMB);
    transpose_v<<<dim3(32, 16), 256, 0, stream>>>(v_s, vT);
    attn_mfma<<<dim3(32, 16), 256, 0, stream>>>(q_s, k_s, vT, r_b, rwb, rrb, ctx_b);
    gemm_bf16<2><<<dim3(4, 32), 256, 0, stream>>>(ctx_b, w_outb, b_out, d_out, nullptr, nullptr, EMB);
}

// Round 11
// 205.010 us; speedup vs baseline: 1.5243x; 1.0673x over previous
//
#include <hip/hip_runtime.h>

#define T_SEQ 2048
#define BATCH 2
#define HEADS 8
#define DHEAD 64
#define EMB   512

typedef __attribute__((ext_vector_type(8))) short short8;
typedef __attribute__((ext_vector_type(4))) float floatx4;
typedef __attribute__((ext_vector_type(8))) unsigned short ushort8;
typedef __attribute__((ext_vector_type(4))) unsigned short ushort4v;

// RNE convert (cold paths)
__device__ __forceinline__ unsigned short f2b(float f) {
    union { float f; unsigned u; } v; v.f = f;
    unsigned r = v.u + 0x7fffu + ((v.u >> 16) & 1u);
    return (unsigned short)(r >> 16);
}
// 1-op truncating convert (hot paths)
__device__ __forceinline__ unsigned short f2bt(float f) {
    union { float f; unsigned u; } v; v.f = f;
    return (unsigned short)(v.u >> 16);
}
__device__ __forceinline__ float b2f(unsigned short s) {
    union { unsigned u; float f; } v; v.u = ((unsigned)s) << 16; return v.f;
}
__device__ __forceinline__ short8 ld_frag(const unsigned short* p) {
    ushort4v lo = *(const ushort4v*)p;
    ushort4v hi = *(const ushort4v*)(p + 4);
    short8 r;
    r[0] = lo[0]; r[1] = lo[1]; r[2] = lo[2]; r[3] = lo[3];
    r[4] = hi[0]; r[5] = hi[1]; r[6] = hi[2]; r[7] = hi[3];
    return r;
}
__device__ __forceinline__ void st8(unsigned short* p, ushort8 v) {
    ushort4v lo = { v[0], v[1], v[2], v[3] };
    ushort4v hi = { v[4], v[5], v[6], v[7] };
    *(ushort4v*)p = lo;
    *(ushort4v*)(p + 4) = hi;
}
#define MFMA16(a, b, c) __builtin_amdgcn_mfma_f32_16x16x32_bf16(a, b, c, 0, 0, 0)

// ---------------------------------------------------------------------------
// One-shot fp32 -> bf16 conversion of all 5 tensors.
// ---------------------------------------------------------------------------
__global__ __launch_bounds__(256)
void cvt_all(const float* __restrict__ s0, const float* __restrict__ s1,
             const float* __restrict__ s2, const float* __restrict__ s3,
             const float* __restrict__ s4,
             unsigned short* __restrict__ d0, unsigned short* __restrict__ d1,
             unsigned short* __restrict__ d2, unsigned short* __restrict__ d3,
             unsigned short* __restrict__ d4)
{
    const int i = blockIdx.x * 256 + threadIdx.x;
    const float* s; unsigned short* d; int off;
    if      (i <  524288) { s = s0; d = d0; off = i; }
    else if (i <  786432) { s = s1; d = d1; off = i -  524288; }
    else if (i <  983040) { s = s2; d = d2; off = i -  786432; }
    else if (i < 1048576) { s = s3; d = d3; off = i -  983040; }
    else if (i < 1114112) { s = s4; d = d4; off = i - 1048576; }
    else return;
    const float4 v = ((const float4*)s)[off];
    ushort4v o = { f2b(v.x), f2b(v.y), f2b(v.z), f2b(v.w) };
    ((ushort4v*)d)[off] = o;
}

// ---------------------------------------------------------------------------
// Fused QKV + pos projection GEMM (448 blocks, one dispatch), 128x128 tiles,
// BK=64 (16 barrier-drains/block instead of 32), 4 waves 2x2.
//   blocks 0..383:  QKV  (bx=id%12, by=id/12)  A=inb,  B=w_inb,  K=512
//     bn <  1024 : scatter q_s/k_s bf16 [B,H,T,D] (coalesced dd-contiguous)
//     bn >= 1024 : V -> epilogue LDS transpose -> vT [B,H,D,T] (coalesced t)
//   blocks 384..447: pos (bx=(id-384)&3, by=(id-384)>>2) -> r bf16 [R,E]
// LDS: staging As@0, Bs@8704 (128x68 each, 34.8 KB); V blocks reuse the same
// region after the k-loop as a 128x131 transpose buffer (33.5 KB).
// ---------------------------------------------------------------------------
__global__ __launch_bounds__(256)
void gemm_qkv_pos(const unsigned short* __restrict__ inb, const unsigned short* __restrict__ w_inb,
                  const float* __restrict__ b_in,
                  const unsigned short* __restrict__ posb, const unsigned short* __restrict__ w_posb,
                  const float* __restrict__ b_pos,
                  unsigned short* __restrict__ q_s, unsigned short* __restrict__ k_s,
                  unsigned short* __restrict__ vT, unsigned short* __restrict__ r_b)
{
    __shared__ unsigned short shmem[17408];     // As@0, Bs@8704 | tb (128x131)
    unsigned short* As = shmem;
    unsigned short* Bs = shmem + 8704;
    unsigned short* tb = shmem;

    const int id = blockIdx.x;
    const bool isPos = (id >= 384);
    const int bx = isPos ? ((id - 384) & 3) : (id % 12);
    const int by = isPos ? ((id - 384) >> 2) : (id / 12);
    const unsigned short* A = isPos ? posb : inb;
    const unsigned short* B = isPos ? w_posb : w_inb;
    const float* bias = isPos ? b_pos : b_in;

    const int bm  = by * 128;
    const int bn  = bx * 128;
    const int tid = threadIdx.x;
    const int lane = tid & 63, w = tid >> 6;
    const int m16 = lane & 15, quad = lane >> 4;
    const int wm = (w & 1) * 64, wn = (w >> 1) * 64;

    floatx4 acc[4][4];
    #pragma unroll
    for (int i = 0; i < 4; ++i)
        #pragma unroll
        for (int j = 0; j < 4; ++j) acc[i][j] = (floatx4){0.f, 0.f, 0.f, 0.f};

    for (int k0 = 0; k0 < 512; k0 += 64) {
        #pragma unroll
        for (int s = tid; s < 1024; s += 256) {
            const int row = s >> 3, c = (s & 7) * 8;
            st8(&As[row * 68 + c], *(const ushort8*)(A + (size_t)(bm + row) * 512 + k0 + c));
            st8(&Bs[row * 68 + c], *(const ushort8*)(B + (size_t)(bn + row) * 512 + k0 + c));
        }
        __syncthreads();
        #pragma unroll
        for (int ks = 0; ks < 2; ++ks) {
            short8 af[4], bf[4];
            #pragma unroll
            for (int f = 0; f < 4; ++f) {
                af[f] = ld_frag(&As[(wm + f * 16 + m16) * 68 + ks * 32 + quad * 8]);
                bf[f] = ld_frag(&Bs[(wn + f * 16 + m16) * 68 + ks * 32 + quad * 8]);
            }
            #pragma unroll
            for (int fm = 0; fm < 4; ++fm)
                #pragma unroll
                for (int fn = 0; fn < 4; ++fn)
                    acc[fm][fn] = MFMA16(af[fm], bf[fn], acc[fm][fn]);
        }
        __syncthreads();
    }

    if (isPos) {
        #pragma unroll
        for (int fn = 0; fn < 4; ++fn) {
            const int n = bn + wn + fn * 16 + m16;
            const float bv = bias[n];
            #pragma unroll
            for (int fm = 0; fm < 4; ++fm)
                #pragma unroll
                for (int rgi = 0; rgi < 4; ++rgi) {
                    const int m = bm + wm + fm * 16 + quad * 4 + rgi;
                    r_b[(size_t)m * EMB + n] = f2b(acc[fm][fn][rgi] + bv);
                }
        }
    } else if (bn < 1024) {
        // q/k scatter (coalesced: dd = n&63 contiguous across m16)
        #pragma unroll
        for (int fn = 0; fn < 4; ++fn) {
            const int n = bn + wn + fn * 16 + m16;
            const float bv = bias[n];
            const int reg = n >> 9, c = n & 511, h = c >> 6, dd = c & 63;
            unsigned short* dst = reg == 0 ? q_s : k_s;
            #pragma unroll
            for (int fm = 0; fm < 4; ++fm)
                #pragma unroll
                for (int rgi = 0; rgi < 4; ++rgi) {
                    const int m = bm + wm + fm * 16 + quad * 4 + rgi;
                    const int t = m >> 1, b = m & 1;
                    dst[((size_t)(b * HEADS + h) * T_SEQ + t) * DHEAD + dd] = f2b(acc[fm][fn][rgi] + bv);
                }
        }
    } else {
        // V: transpose through LDS, write vT [B,H,D,T] coalesced along t
        #pragma unroll
        for (int fn = 0; fn < 4; ++fn) {
            const int nl = wn + fn * 16 + m16;
            const float bv = bias[bn + nl];
            #pragma unroll
            for (int fm = 0; fm < 4; ++fm)
                #pragma unroll
                for (int rgi = 0; rgi < 4; ++rgi) {
                    const int ml = wm + fm * 16 + quad * 4 + rgi;
                    tb[nl * 131 + ml] = f2b(acc[fm][fn][rgi] + bv);
                }
        }
        __syncthreads();
        const int t0g = bm >> 1;
        for (int s2 = tid; s2 < 2048; s2 += 256) {
            const int nl = s2 >> 4;             // 0..127
            const int bsel = (s2 >> 3) & 1;     // batch
            const int j = s2 & 7;               // t-chunk of 8
            ushort8 o;
            #pragma unroll
            for (int k = 0; k < 8; ++k)
                o[k] = tb[nl * 131 + ((j * 8 + k) * 2 + bsel)];
            const int c = bn + nl - 1024, h = c >> 6, dd = c & 63;
            *(ushort8*)(vT + ((size_t)(bsel * HEADS + h) * DHEAD + dd) * T_SEQ + t0g + j * 8) = o;
        }
    }
}

// ---------------------------------------------------------------------------
// Output GEMM: ctx bf16 [4096,512] x w_out -> fp32 out. 128x128, BK=64.
// ---------------------------------------------------------------------------
__global__ __launch_bounds__(256)
void gemm_out(const unsigned short* __restrict__ A, const unsigned short* __restrict__ B,
              const float* __restrict__ bias, float* __restrict__ out)
{
    __shared__ unsigned short As[128 * 68];
    __shared__ unsigned short Bs[128 * 68];
    const int bm  = blockIdx.y * 128;
    const int bn  = blockIdx.x * 128;
    const int tid = threadIdx.x;
    const int lane = tid & 63, w = tid >> 6;
    const int m16 = lane & 15, quad = lane >> 4;
    const int wm = (w & 1) * 64, wn = (w >> 1) * 64;

    floatx4 acc[4][4];
    #pragma unroll
    for (int i = 0; i < 4; ++i)
        #pragma unroll
        for (int j = 0; j < 4; ++j) acc[i][j] = (floatx4){0.f, 0.f, 0.f, 0.f};

    for (int k0 = 0; k0 < 512; k0 += 64) {
        #pragma unroll
        for (int s = tid; s < 1024; s += 256) {
            const int row = s >> 3, c = (s & 7) * 8;
            st8(&As[row * 68 + c], *(const ushort8*)(A + (size_t)(bm + row) * 512 + k0 + c));
            st8(&Bs[row * 68 + c], *(const ushort8*)(B + (size_t)(bn + row) * 512 + k0 + c));
        }
        __syncthreads();
        #pragma unroll
        for (int ks = 0; ks < 2; ++ks) {
            short8 af[4], bf[4];
            #pragma unroll
            for (int f = 0; f < 4; ++f) {
                af[f] = ld_frag(&As[(wm + f * 16 + m16) * 68 + ks * 32 + quad * 8]);
                bf[f] = ld_frag(&Bs[(wn + f * 16 + m16) * 68 + ks * 32 + quad * 8]);
            }
            #pragma unroll
            for (int fm = 0; fm < 4; ++fm)
                #pragma unroll
                for (int fn = 0; fn < 4; ++fn)
                    acc[fm][fn] = MFMA16(af[fm], bf[fn], acc[fm][fn]);
        }
        __syncthreads();
    }

    #pragma unroll
    for (int fn = 0; fn < 4; ++fn) {
        const int n = bn + wn + fn * 16 + m16;
        const float bv = bias[n];
        #pragma unroll
        for (int fm = 0; fm < 4; ++fm)
            #pragma unroll
            for (int rgi = 0; rgi < 4; ++rgi) {
                const int m = bm + wm + fm * 16 + quad * 4 + rgi;
                out[(size_t)m * EMB + n] = acc[fm][fn][rgi] + bv;
            }
    }
}

// ---------------------------------------------------------------------------
// Fused MFMA attention — unchanged from Round 10 (proven 94.8 us).
//   bd[t][s] = QR[t][T-1-t+s] (s<=t) | 0 (s==t+1) | QR[t+1][s-t-2] (s>=t+2)
// LDS (u16): k@0 (2x4352) v@8704 (2x4352) rp@17408 (2x4352) ring@26112
// (64x133). Total 69,248 B -> 2 blocks/CU.
// ---------------------------------------------------------------------------
__global__ __launch_bounds__(256)
void attn_mfma(const unsigned short* __restrict__ qg_, const unsigned short* __restrict__ kg_,
               const unsigned short* __restrict__ vtg_, const unsigned short* __restrict__ rg_,
               const float* __restrict__ rwb, const float* __restrict__ rrb,
               unsigned short* __restrict__ ctx)
{
    const int T   = T_SEQ;
    const int tb  = blockIdx.x;
    const int t0  = tb * 64;
    const int bh  = blockIdx.y;
    const int h   = bh & 7;
    const int b   = bh >> 3;
    const int tid = threadIdx.x;
    const int lane = tid & 63;
    const int w    = tid >> 6;
    const int m16  = lane & 15;
    const int quad = lane >> 4;
    const int ibase = 16 * w + quad * 4;

    __shared__ unsigned short lds[34624];
    unsigned short* ring  = lds + 26112;     // [i][slot], stride 133
    unsigned short* qrw_s = lds;             // pre-loop alias (k buf 0)
    unsigned short* qrr_s = lds + 8704;      // pre-loop alias (v buf 0, 65 rows)

    const unsigned short* qg  = qg_  + ((size_t)bh * T + t0) * DHEAD;
    const unsigned short* kg  = kg_  + (size_t)bh * T * DHEAD;
    const unsigned short* vtg = vtg_ + (size_t)bh * DHEAD * T;
    const unsigned short* rg  = rg_  + h * DHEAD;

    const float QSCALE = 0.125f * 1.44269504089f;
    for (int idx = tid; idx < 65 * 16; idx += 256) {
        const int row = idx >> 4, c = (idx & 15) << 2;
        ushort4v qv = {0, 0, 0, 0};
        if (t0 + row < T) qv = *(const ushort4v*)(qg + row * DHEAD + c);
        const float4 rr = *(const float4*)(rrb + h * DHEAD + c);
        qrr_s[row * 68 + c + 0] = f2b((b2f(qv[0]) + rr.x) * QSCALE);
        qrr_s[row * 68 + c + 1] = f2b((b2f(qv[1]) + rr.y) * QSCALE);
        qrr_s[row * 68 + c + 2] = f2b((b2f(qv[2]) + rr.z) * QSCALE);
        qrr_s[row * 68 + c + 3] = f2b((b2f(qv[3]) + rr.w) * QSCALE);
        if (row < 64) {
            const float4 rw = *(const float4*)(rwb + h * DHEAD + c);
            qrw_s[row * 68 + c + 0] = f2b((b2f(qv[0]) + rw.x) * QSCALE);
            qrw_s[row * 68 + c + 1] = f2b((b2f(qv[1]) + rw.y) * QSCALE);
            qrw_s[row * 68 + c + 2] = f2b((b2f(qv[2]) + rw.z) * QSCALE);
            qrw_s[row * 68 + c + 3] = f2b((b2f(qv[3]) + rw.w) * QSCALE);
        }
    }
    __syncthreads();

    short8 a_ac[2], a_qrl[2], a_qru[2];
    {
        const unsigned short* p0 = &qrw_s[(16 * w + m16) * 68 + quad * 8];
        a_ac[0]  = ld_frag(p0);  a_ac[1]  = ld_frag(p0 + 32);
        const unsigned short* p1 = &qrr_s[(16 * w + m16) * 68 + quad * 8];
        a_qrl[0] = ld_frag(p1);  a_qrl[1] = ld_frag(p1 + 32);
        const unsigned short* p2 = &qrr_s[(16 * w + 1 + m16) * 68 + quad * 8];
        a_qru[0] = ld_frag(p2);  a_qru[1] = ld_frag(p2 + 32);
    }

    const int srow0 = tid >> 3,          scol0 = (tid & 7) * 8;
    const int srow1 = (tid + 256) >> 3,  scol1 = (tid & 7) * 8;

    ushort8 kr[2], vr[2], rr8[2];
    auto prefetch = [&](int s0n) {
        const bool ln = (s0n <= t0);
        const int jb = (ln ? (s0n + T - t0 - 64) : (s0n - t0 - 65)) + 64;
        int j0 = jb + srow0; j0 = j0 < 0 ? 0 : (j0 > T - 1 ? T - 1 : j0);
        int j1 = jb + srow1; j1 = j1 < 0 ? 0 : (j1 > T - 1 ? T - 1 : j1);
        kr[0]  = *(const ushort8*)(kg + (size_t)(s0n + srow0) * DHEAD + scol0);
        kr[1]  = *(const ushort8*)(kg + (size_t)(s0n + srow1) * DHEAD + scol1);
        vr[0]  = *(const ushort8*)(vtg + (size_t)srow0 * T + s0n + scol0);
        vr[1]  = *(const ushort8*)(vtg + (size_t)srow1 * T + s0n + scol1);
        rr8[0] = *(const ushort8*)(rg + (size_t)j0 * EMB + scol0);
        rr8[1] = *(const ushort8*)(rg + (size_t)j1 * EMB + scol1);
    };
    auto store_bufs = [&](int q) {
        unsigned short* kb = lds + q * 4352;
        unsigned short* vb = lds + 8704 + q * 4352;
        unsigned short* rb = lds + 17408 + q * 4352;
        st8(&kb[srow0 * 68 + scol0], kr[0]);
        st8(&kb[srow1 * 68 + scol1], kr[1]);
        st8(&vb[srow0 * 68 + scol0], vr[0]);
        st8(&vb[srow1 * 68 + scol1], vr[1]);
        st8(&rb[srow0 * 68 + scol0], rr8[0]);
        st8(&rb[srow1 * 68 + scol1], rr8[1]);
    };
    auto stage_to = [&](unsigned short* dstb, int jbase) {
        #pragma unroll
        for (int idx = tid; idx < 512; idx += 256) {
            const int row = idx >> 3, c = (idx & 7) * 8;
            int j = jbase + row; j = j < 0 ? 0 : (j > T - 1 ? T - 1 : j);
            st8(&dstb[row * 68 + c], *(const ushort8*)(rg + (size_t)j * EMB + c));
        }
    };
    auto qr_half = [&](const unsigned short* rsb, const short8* aq, int slotbase) {
        #pragma unroll
        for (int cc = 0; cc < 4; ++cc) {
            floatx4 q4 = (floatx4){0.f, 0.f, 0.f, 0.f};
            #pragma unroll
            for (int ks = 0; ks < 2; ++ks) {
                short8 bfr = ld_frag(&rsb[(16 * cc + m16) * 68 + ks * 32 + quad * 8]);
                q4 = MFMA16(aq[ks], bfr, q4);
            }
            #pragma unroll
            for (int rgi = 0; rgi < 4; ++rgi)
                ring[(ibase + rgi) * 133 + slotbase + 16 * cc + m16] = f2bt(q4[rgi]);
        }
    };

    floatx4 O[4];
    float lrun[4];
    #pragma unroll
    for (int ct = 0; ct < 4; ++ct) O[ct] = (floatx4){0.f, 0.f, 0.f, 0.f};
    #pragma unroll
    for (int rgi = 0; rgi < 4; ++rgi) lrun[rgi] = 0.f;

    {
        stage_to(lds + 17408 + 4352, T - t0 - 64);
        prefetch(0);
        __syncthreads();
        qr_half(lds + 17408 + 4352, a_qrl, 0);
        store_bufs(0);
        __syncthreads();
    }

    for (int na = 0; na < T / 64; ++na) {
        const int s0 = na * 64;
        const int p = na & 1;
        unsigned short* kb = lds + p * 4352;
        unsigned short* vb = lds + 8704 + p * 4352;
        unsigned short* rp = lds + 17408 + p * 4352;
        const bool lower = (s0 <= t0);
        const int nph    = lower ? (s0 >> 6) : ((s0 - t0) >> 6);
        const int rbase  = (nph & 1) * 64;
        const int wbase  = 64 - rbase;
        const bool hasNext = (na + 1 < T / 64);

        floatx4 acf[4];
        #pragma unroll
        for (int ct = 0; ct < 4; ++ct) {
            acf[ct] = (floatx4){0.f, 0.f, 0.f, 0.f};
            #pragma unroll
            for (int ks = 0; ks < 2; ++ks) {
                short8 bfr = ld_frag(&kb[(16 * ct + m16) * 68 + ks * 32 + quad * 8]);
                acf[ct] = MFMA16(a_ac[ks], bfr, acf[ct]);
            }
        }
        qr_half(rp, lower ? a_qrl : a_qru, wbase);
        if (hasNext) prefetch(s0 + 64);
        __syncthreads();                       // B1

        if (s0 != t0) {
            #pragma unroll
            for (int ct = 0; ct < 4; ++ct) {
                #pragma unroll
                for (int rgi = 0; rgi < 4; ++rgi) {
                    const int i = ibase + rgi;
                    const int slot = ((63 - i + 16 * ct + m16) + rbase) & 127;
                    acf[ct][rgi] += b2f(ring[i * 133 + slot]);
                }
            }
            if (s0 == t0 + 64 && lane == 48 && w == 3)
                acf[0][3] -= b2f(ring[63 * 133 + (rbase & 127)]);
        } else {
            #pragma unroll
            for (int ct = 0; ct < 4; ++ct) {
                #pragma unroll
                for (int rgi = 0; rgi < 4; ++rgi) {
                    const int i = ibase + rgi, u = 16 * ct + m16;
                    if (u <= i) acf[ct][rgi] += b2f(ring[i * 133 + (((63 - i + u) + rbase) & 127)]);
                }
            }
            unsigned short* rpo = lds + 17408 + (1 - p) * 4352;
            __syncthreads();                   // Bd1
            stage_to(rpo, -1);
            __syncthreads();                   // Bd2
            qr_half(rpo, a_qru, 64);
            __syncthreads();                   // Bd3
            #pragma unroll
            for (int ct = 0; ct < 4; ++ct) {
                #pragma unroll
                for (int rgi = 0; rgi < 4; ++rgi) {
                    const int i = ibase + rgi, u = 16 * ct + m16;
                    if (u >= i + 2) acf[ct][rgi] += b2f(ring[i * 133 + 63 - i + u]);
                }
            }
        }

        #pragma unroll
        for (int rgi = 0; rgi < 4; ++rgi) {
            #pragma unroll
            for (int ct = 0; ct < 4; ++ct) {
                const float pv = exp2f(acf[ct][rgi]);
                acf[ct][rgi] = pv;
                lrun[rgi] += pv;
            }
        }
        #pragma unroll
        for (int ct = 0; ct < 4; ++ct)
            #pragma unroll
            for (int rgi = 0; rgi < 4; ++rgi)
                rp[(ibase + rgi) * 68 + 16 * ct + m16] = f2bt(acf[ct][rgi]);
        if (hasNext) store_bufs(1 - p);
        __syncthreads();                       // B2

        short8 ap[2];
        {
            const unsigned short* pp = &rp[(16 * w + m16) * 68 + quad * 8];
            ap[0] = ld_frag(pp); ap[1] = ld_frag(pp + 32);
        }
        #pragma unroll
        for (int ct = 0; ct < 4; ++ct) {
            #pragma unroll
            for (int ks = 0; ks < 2; ++ks) {
                short8 bfr = ld_frag(&vb[(16 * ct + m16) * 68 + ks * 32 + quad * 8]);
                O[ct] = MFMA16(ap[ks], bfr, O[ct]);
            }
        }
    }

    #pragma unroll
    for (int rgi = 0; rgi < 4; ++rgi) {
        float l = lrun[rgi];
        #pragma unroll
        for (int off = 1; off < 16; off <<= 1)
            l += __shfl_xor(l, off);
        const float inv = 1.f / l;
        const int t = t0 + ibase + rgi;
        #pragma unroll
        for (int ct = 0; ct < 4; ++ct)
            ctx[((size_t)t * BATCH + b) * EMB + h * DHEAD + 16 * ct + m16] = f2bt(O[ct][rgi] * inv);
    }
}

// ---------------------------------------------------------------------------
// Workspace (ushort offsets), 15,990,784 ush = 31.98 MB:
//   0        inb     2,097,152
//   2097152  posb    1,048,576
//   3145728  w_inb     786,432
//   3932160  w_posb    262,144
//   4194304  (free)  2,097,152
//   6291456  w_outb    262,144
//   6553600  q_s     2,097,152
//   8650752  k_s     2,097,152
//   10747904 vT      2,097,152   (written directly by gemm_qkv_pos epilogue)
//   12845056 r_b     1,048,576
//   13893632 ctx_b   2,097,152
// ---------------------------------------------------------------------------
extern "C" void kernel_launch(void* const* d_in, const int* in_sizes, int n_in,
                              void* d_out, int out_size, void* d_ws, size_t ws_size,
                              hipStream_t stream)
{
    const float* input = (const float*)d_in[0];
    const float* pos   = (const float*)d_in[1];
    const float* w_in  = (const float*)d_in[2];
    const float* w_out = (const float*)d_in[3];
    const float* w_pos = (const float*)d_in[4];
    const float* b_in  = (const float*)d_in[5];
    const float* b_out = (const float*)d_in[6];
    const float* b_pos = (const float*)d_in[7];
    const float* rwb   = (const float*)d_in[8];
    const float* rrb   = (const float*)d_in[9];

    unsigned short* ws     = (unsigned short*)d_ws;
    unsigned short* inb    = ws;
    unsigned short* posb   = ws + 2097152;
    unsigned short* w_inb  = ws + 3145728;
    unsigned short* w_posb = ws + 3932160;
    unsigned short* w_outb = ws + 6291456;
    unsigned short* q_s    = ws + 6553600;
    unsigned short* k_s    = ws + 8650752;
    unsigned short* vT     = ws + 10747904;
    unsigned short* r_b    = ws + 12845056;
    unsigned short* ctx_b  = ws + 13893632;

    cvt_all<<<4352, 256, 0, stream>>>(input, pos, w_in, w_pos, w_out,
                                      inb, posb, w_inb, w_posb, w_outb);
    gemm_qkv_pos<<<448, 256, 0, stream>>>(inb, w_inb, b_in, posb, w_posb, b_pos,
                                          q_s, k_s, vT, r_b);
    attn_mfma<<<dim3(32, 16), 256, 0, stream>>>(q_s, k_s, vT, r_b, rwb, rrb, ctx_b);
    gemm_out<<<dim3(4, 32), 256, 0, stream>>>(ctx_b, w_outb, b_out, (float*)d_out);
}